// Round 8
// baseline (420.080 us; speedup 1.0000x reference)
//
#include <hip/hip_runtime.h>
#include <hip/hip_fp16.h>

// CompositeValueNoise R14 (resubmit; previous round was a container-
// acquisition infra failure, no measurement). R13 base (verified 187.9us;
// main4 52us). Changes, each independently conservative:
//  1. main4 evaluates ALL levels from LDS: V16/V32 bucket slices staged as
//     float4 (288B + 1.2KB, fp32 -> numerics unchanged) with CLAMPED
//     bucket-slice interp; kills 16 scattered global loads/pt (latency-
//     bound: VALU 36%, HBM 25% -> neither pipe saturated).
//  2. cvn_hist atomically accumulates chunk sums into S (integer adds,
//     bit-identical S) -> cvn_scan_a deleted.
//  3. cvn_scatter: 2-barrier shfl scan replaces 20-barrier Hillis-Steele
//     (identical cnt values -> identical sorted bytes); sc[] dropped.
// Hazard watch: if main4 WRITE_SIZE ~294MB reappears, freeze main4.

#define NB 1024                // 16 x 8 x 8 buckets
#define PTS_PER_BLK 4096
#define CHUNK 32
#define SC_THREADS 1024
#define SC_PPT (PTS_PER_BLK / SC_THREADS)
#define H_THREADS 256
#define H_PPT (PTS_PER_BLK / H_THREADS)
#define MT 512                 // main kernel threads

__device__ __forceinline__ int bucket_of(float px, float py, float pz) {
    int ix = min(max((int)(px * 16.0f), 0), 15);
    int iy = min(max((int)(py * 8.0f), 0), 7);
    int iz = min(max((int)(pz * 8.0f), 0), 7);
    return (ix * 8 + iy) * 8 + iz;
}

// Per-block counts -> P[b][q]; chunk sums accumulated into S[c][q]
// (S pre-zeroed; integer atomic adds -> bit-identical to old scan_a).
__global__ void __launch_bounds__(H_THREADS)
cvn_hist(const float* __restrict__ x, int* __restrict__ P,
         int* __restrict__ S, int n) {
    __shared__ int cnt[NB];
    int t = threadIdx.x;
    for (int q = t; q < NB; q += H_THREADS) cnt[q] = 0;
    __syncthreads();
    int base = blockIdx.x * PTS_PER_BLK;
    for (int k = 0; k < H_PPT; ++k) {
        int i = base + k * H_THREADS + t;
        if (i < n)
            atomicAdd(&cnt[bucket_of(x[3 * i], x[3 * i + 1], x[3 * i + 2])], 1);
    }
    __syncthreads();
    int* Pb = P + (size_t)blockIdx.x * NB;
    int* Sc = S + (size_t)(blockIdx.x / CHUNK) * NB;
    for (int q = t; q < NB; q += H_THREADS) {
        int v = cnt[q];
        Pb[q] = v;
        if (v) atomicAdd(&Sc[q], v);
    }
}

// After: S[c][q] = Texcl[q] + exclusive chunk prefix; S[0][q] = bucket base.
__global__ void __launch_bounds__(NB)
cvn_scan_b(int* __restrict__ S, int nch) {
    __shared__ int part[16];
    int t = threadIdx.x;
    int lane = t & 63, wid = t >> 6;
    int acc = 0;
    for (int c = 0; c < nch; ++c) {
        int v = S[(size_t)c * NB + t];
        S[(size_t)c * NB + t] = acc;
        acc += v;
    }
    int sum = acc;
    #pragma unroll
    for (int off = 1; off < 64; off <<= 1) {
        int v = __shfl_up(sum, off, 64);
        if (lane >= off) sum += v;
    }
    if (lane == 63) part[wid] = sum;
    __syncthreads();
    if (t < 16) {
        int p = part[t];
        int s2 = p;
        #pragma unroll
        for (int off = 1; off < 16; off <<= 1) {
            int v = __shfl_up(s2, off, 64);
            if (t >= off) s2 += v;
        }
        part[t] = s2 - p;          // exclusive wave offset
    }
    __syncthreads();
    int texcl = part[wid] + (sum - acc);   // global exclusive prefix at t
    for (int c = 0; c < nch; ++c) S[(size_t)c * NB + t] += texcl;
}

__global__ void __launch_bounds__(256)
cvn_scan_c(int* __restrict__ P, const int* __restrict__ S, int nblk) {
    int q = blockIdx.x * 256 + threadIdx.x;
    int c = blockIdx.y;
    int b0 = c * CHUNK, b1 = min(b0 + CHUNK, nblk);
    int run = S[(size_t)c * NB + q];
    for (int b = b0; b < b1; ++b) {
        int v = P[(size_t)b * NB + q];
        P[(size_t)b * NB + q] = run;
        run += v;
    }
}

__global__ void __launch_bounds__(SC_THREADS)
cvn_scatter(const float* __restrict__ x, const int* __restrict__ P,
            float4* __restrict__ sorted, int n) {
    __shared__ int cnt[NB];
    __shared__ int place[NB];
    __shared__ int Pb[NB];
    __shared__ int part[16];
    __shared__ float4 payload[PTS_PER_BLK];
    __shared__ unsigned short bkt[PTS_PER_BLK];
    int t = threadIdx.x, b = blockIdx.x;
    int lane = t & 63, wid = t >> 6;
    int base = b * PTS_PER_BLK;
    cnt[t] = 0; place[t] = 0;
    Pb[t] = P[(size_t)b * NB + t];
    __syncthreads();

    float px[SC_PPT], py[SC_PPT], pz[SC_PPT];
    int qq[SC_PPT];
    #pragma unroll
    for (int k = 0; k < SC_PPT; ++k) {
        int i = base + k * SC_THREADS + t;
        if (i < n) {
            px[k] = x[3 * i]; py[k] = x[3 * i + 1]; pz[k] = x[3 * i + 2];
            qq[k] = bucket_of(px[k], py[k], pz[k]);
            atomicAdd(&cnt[qq[k]], 1);
        } else qq[k] = -1;
    }
    __syncthreads();

    // Exclusive scan of cnt[1024]: per-wave shfl scan + 16-partial scan
    // (identical values to the old Hillis-Steele).
    int c0 = cnt[t];
    int sum = c0;
    #pragma unroll
    for (int off = 1; off < 64; off <<= 1) {
        int v = __shfl_up(sum, off, 64);
        if (lane >= off) sum += v;
    }
    if (lane == 63) part[wid] = sum;
    __syncthreads();
    if (t < 16) {
        int p = part[t];
        int s2 = p;
        #pragma unroll
        for (int off = 1; off < 16; off <<= 1) {
            int v = __shfl_up(s2, off, 64);
            if (t >= off) s2 += v;
        }
        part[t] = s2 - p;          // exclusive wave offset
    }
    __syncthreads();
    cnt[t] = part[wid] + (sum - c0);   // exclusive staging start
    __syncthreads();

    #pragma unroll
    for (int k = 0; k < SC_PPT; ++k) {
        if (qq[k] >= 0) {
            int q = qq[k];
            int lp = atomicAdd(&place[q], 1);
            int slot = cnt[q] + lp;
            int i = base + k * SC_THREADS + t;
            payload[slot] = make_float4(px[k], py[k], pz[k], __int_as_float(i));
            bkt[slot] = (unsigned short)q;
        }
    }
    __syncthreads();

    int total = min(n - base, PTS_PER_BLK);
    #pragma unroll
    for (int k = 0; k < SC_PPT; ++k) {
        int j = k * SC_THREADS + t;
        if (j < total) {
            int q = bkt[j];
            sorted[Pb[q] + (j - cnt[q])] = payload[j];
        }
    }
}

__device__ __forceinline__ float4 lerp4(float4 a, float4 b, float w) {
    return make_float4(a.x + w * (b.x - a.x),
                       a.y + w * (b.y - a.y),
                       a.z + w * (b.z - a.z),
                       a.w + w * (b.w - a.w));
}

template <int RES>
__device__ __forceinline__ float4 level_val(const float4* __restrict__ V,
                                            float px, float py, float pz) {
    constexpr int S = RES + 1;
    float xs = fmodf(px * (float)RES, (float)RES);
    float ys = fmodf(py * (float)RES, (float)RES);
    float zs = fmodf(pz * (float)RES, (float)RES);
    float fx = floorf(xs), fy = floorf(ys), fz = floorf(zs);
    float tx = xs - fx, ty = ys - fy, tz = zs - fz;
    int ix = (int)fx, iy = (int)fy, iz = (int)fz;

    float wx = (3.0f - 2.0f * tx) * tx * tx;
    float wy = (3.0f - 2.0f * ty) * ty * ty;
    float wz = (3.0f - 2.0f * tz) * tz * tz;

    int base = (ix * S + iy) * S + iz;
    const float4* p0 = V + base;
    const float4* p1 = p0 + S * S;

    float4 c000 = p0[0];
    float4 c001 = p0[1];
    float4 c010 = p0[S];
    float4 c011 = p0[S + 1];
    float4 c100 = p1[0];
    float4 c101 = p1[1];
    float4 c110 = p1[S];
    float4 c111 = p1[S + 1];

    float4 m00 = lerp4(c000, c100, wx);
    float4 m01 = lerp4(c001, c101, wx);
    float4 m10 = lerp4(c010, c110, wx);
    float4 m11 = lerp4(c011, c111, wx);
    float4 n0  = lerp4(m00, m10, wy);
    float4 n1  = lerp4(m01, m11, wy);
    return lerp4(n0, n1, wz);
}

__device__ __forceinline__ float4 composite(const float4* __restrict__ V16,
                                            const float4* __restrict__ V32,
                                            const float4* __restrict__ V64,
                                            const float4* __restrict__ V128,
                                            float px, float py, float pz) {
    float4 acc = level_val<16>(V16, px, py, pz);
    float4 v;
    v = level_val<32>(V32, px, py, pz);
    acc.x += 0.5f * v.x; acc.y += 0.5f * v.y; acc.z += 0.5f * v.z; acc.w += 0.5f * v.w;
    v = level_val<64>(V64, px, py, pz);
    acc.x += 0.25f * v.x; acc.y += 0.25f * v.y; acc.z += 0.25f * v.z; acc.w += 0.25f * v.w;
    v = level_val<128>(V128, px, py, pz);
    acc.x += 0.125f * v.x; acc.y += 0.125f * v.y; acc.z += 0.125f * v.z; acc.w += 0.125f * v.w;
    return acc;
}

// fp16 node load: 8B (4 halves) via one ds_read_b64.
__device__ __forceinline__ float4 ldh4(const uint2* p) {
    uint2 u = *p;
    __half2 h0 = *reinterpret_cast<const __half2*>(&u.x);
    __half2 h1 = *reinterpret_cast<const __half2*>(&u.y);
    float2 f0 = __half22float2(h0);
    float2 f1 = __half22float2(h1);
    return make_float4(f0.x, f0.y, f1.x, f1.y);
}

__device__ __forceinline__ uint2 sth4(float4 v) {
    __half2 h0 = __floats2half2_rn(v.x, v.y);
    __half2 h1 = __floats2half2_rn(v.z, v.w);
    uint2 u;
    u.x = *reinterpret_cast<unsigned int*>(&h0);
    u.y = *reinterpret_cast<unsigned int*>(&h1);
    return u;
}

// Trilinear interp from an fp16 LDS slice covering one FULL coarse bucket
// (1/16 x 1/8 x 1/8). CX=RES/16 cells in x, CY=CZ=RES/8 in y/z. Clamped.
template <int RES>
__device__ __forceinline__ float4 lds_interp_h(const uint2* s,
                                               float px, float py, float pz,
                                               int ix16, int iy8, int iz8) {
    constexpr int CX = RES / 16, CY = RES / 8, CZ = RES / 8;
    constexpr int DY = CY + 1, DZ = CZ + 1;
    float xs = px * (float)RES;
    float ys = py * (float)RES;
    float zs = pz * (float)RES;
    int ixg = (int)xs, iyg = (int)ys, izg = (int)zs;
    float tx = xs - (float)ixg, ty = ys - (float)iyg, tz = zs - (float)izg;
    int lx = min(max(ixg - ix16 * CX, 0), CX - 1);
    int ly = min(max(iyg - iy8 * CY, 0), CY - 1);
    int lz = min(max(izg - iz8 * CZ, 0), CZ - 1);

    float wx = (3.0f - 2.0f * tx) * tx * tx;
    float wy = (3.0f - 2.0f * ty) * ty * ty;
    float wz = (3.0f - 2.0f * tz) * tz * tz;

    const uint2* p0 = s + (lx * DY + ly) * DZ + lz;
    const uint2* p1 = p0 + DY * DZ;
    float4 c000 = ldh4(p0),      c001 = ldh4(p0 + 1);
    float4 c010 = ldh4(p0 + DZ), c011 = ldh4(p0 + DZ + 1);
    float4 c100 = ldh4(p1),      c101 = ldh4(p1 + 1);
    float4 c110 = ldh4(p1 + DZ), c111 = ldh4(p1 + DZ + 1);

    float4 m00 = lerp4(c000, c100, wx);
    float4 m01 = lerp4(c001, c101, wx);
    float4 m10 = lerp4(c010, c110, wx);
    float4 m11 = lerp4(c011, c111, wx);
    float4 n0  = lerp4(m00, m10, wy);
    float4 n1  = lerp4(m01, m11, wy);
    return lerp4(n0, n1, wz);
}

// Same, float4 (fp32) LDS slice — for the high-weight 16/32 levels.
template <int RES>
__device__ __forceinline__ float4 lds_interp_b(const float4* s,
                                               float px, float py, float pz,
                                               int ix16, int iy8, int iz8) {
    constexpr int CX = RES / 16, CY = RES / 8, CZ = RES / 8;
    constexpr int DY = CY + 1, DZ = CZ + 1;
    float xs = px * (float)RES;
    float ys = py * (float)RES;
    float zs = pz * (float)RES;
    int ixg = (int)xs, iyg = (int)ys, izg = (int)zs;
    float tx = xs - (float)ixg, ty = ys - (float)iyg, tz = zs - (float)izg;
    int lx = min(max(ixg - ix16 * CX, 0), CX - 1);
    int ly = min(max(iyg - iy8 * CY, 0), CY - 1);
    int lz = min(max(izg - iz8 * CZ, 0), CZ - 1);

    float wx = (3.0f - 2.0f * tx) * tx * tx;
    float wy = (3.0f - 2.0f * ty) * ty * ty;
    float wz = (3.0f - 2.0f * tz) * tz * tz;

    const float4* p0 = s + (lx * DY + ly) * DZ + lz;
    const float4* p1 = p0 + DY * DZ;
    float4 c000 = p0[0],  c001 = p0[1];
    float4 c010 = p0[DZ], c011 = p0[DZ + 1];
    float4 c100 = p1[0],  c101 = p1[1];
    float4 c110 = p1[DZ], c111 = p1[DZ + 1];

    float4 m00 = lerp4(c000, c100, wx);
    float4 m01 = lerp4(c001, c101, wx);
    float4 m10 = lerp4(c010, c110, wx);
    float4 m11 = lerp4(c011, c111, wx);
    float4 n0  = lerp4(m00, m10, wy);
    float4 n1  = lerp4(m01, m11, wy);
    return lerp4(n0, n1, wz);
}

// One WG per 1/16x1/8x1/8 bucket. ALL levels staged to LDS: V64/V128 fp16
// (24KB), V16/V32 float4 (1.5KB). Zero global loads in the point loop
// besides the coalesced sorted read; out[orig] scattered write (idx in .w).
__global__ void __launch_bounds__(MT, 8)
cvn_main4(const float4* __restrict__ sorted, const int* __restrict__ Tbase,
          const float4* __restrict__ V16, const float4* __restrict__ V32,
          const float4* __restrict__ V64, const float4* __restrict__ V128,
          float4* __restrict__ out, int n) {
    __shared__ uint2 s128[9 * 17 * 17];   // 2601 -> 20808 B
    __shared__ uint2 s64[5 * 9 * 9];      //  405 ->  3240 B
    __shared__ float4 s32f[3 * 5 * 5];    //   75 ->  1200 B
    __shared__ float4 s16f[2 * 3 * 3];    //   18 ->   288 B
    int t = threadIdx.x, b = blockIdx.x;

    // XCD-compact mapping: b&7 -> octant of the 16x8x8 bucket space
    // (8x4x4 buckets each); g enumerated x-slowest so the ~64 resident
    // buckets per XCD form a compact region (~2.2 MB V128 slice < 4MB L2).
    int ox = b & 1, oy = (b >> 1) & 1, oz = (b >> 2) & 1;
    int g  = b >> 3;                         // 0..127
    int gx = g >> 4, gy = (g >> 2) & 3, gz = g & 3;
    int ix16 = ox * 8 + gx, iy8 = oy * 4 + gy, iz8 = oz * 4 + gz;
    int q = (ix16 * 8 + iy8) * 8 + iz8;

    int base = Tbase[q];
    int end  = (q == NB - 1) ? n : Tbase[q + 1];
    int len  = end - base;

    // Stage: V128 9x17x17 fp16, V64 5x9x9 fp16, V32 3x5x5 f32, V16 2x3x3 f32.
    int bx = ix16 * 8, by = iy8 * 16, bz = iz8 * 16;
    for (int u = t; u < 2601; u += MT) {
        int a = u / 289, r = u - a * 289;
        int bb = r / 17, c = r - bb * 17;
        s128[u] = sth4(V128[((size_t)(bx + a) * 129 + (by + bb)) * 129
                            + (bz + c)]);
    }
    for (int u = t; u < 405; u += MT) {
        int a = u / 81, r = u - a * 81;
        int bb = r / 9, c = r - bb * 9;
        s64[u] = sth4(V64[((size_t)(ix16 * 4 + a) * 65 + (iy8 * 8 + bb)) * 65
                          + (iz8 * 8 + c)]);
    }
    for (int u = t; u < 75; u += MT) {
        int a = u / 25, r = u - a * 25;
        int bb = r / 5, c = r - bb * 5;
        s32f[u] = V32[((size_t)(ix16 * 2 + a) * 33 + (iy8 * 4 + bb)) * 33
                      + (iz8 * 4 + c)];
    }
    for (int u = t; u < 18; u += MT) {
        int a = u / 9, r = u - a * 9;
        int bb = r / 3, c = r - bb * 3;
        s16f[u] = V16[((size_t)(ix16 + a) * 17 + (iy8 * 2 + bb)) * 17
                      + (iz8 * 2 + c)];
    }
    __syncthreads();

    // Stream points: coalesced read; all levels via LDS; scattered out write.
    for (int p = t; p < len; p += MT) {
        float4 pt = sorted[base + p];
        float4 acc = lds_interp_b<16>(s16f, pt.x, pt.y, pt.z, ix16, iy8, iz8);
        float4 v;
        v = lds_interp_b<32>(s32f, pt.x, pt.y, pt.z, ix16, iy8, iz8);
        acc.x += 0.5f * v.x; acc.y += 0.5f * v.y;
        acc.z += 0.5f * v.z; acc.w += 0.5f * v.w;
        v = lds_interp_h<64>(s64, pt.x, pt.y, pt.z, ix16, iy8, iz8);
        acc.x += 0.25f * v.x; acc.y += 0.25f * v.y;
        acc.z += 0.25f * v.z; acc.w += 0.25f * v.w;
        v = lds_interp_h<128>(s128, pt.x, pt.y, pt.z, ix16, iy8, iz8);
        acc.x += 0.125f * v.x; acc.y += 0.125f * v.y;
        acc.z += 0.125f * v.z; acc.w += 0.125f * v.w;
        out[__float_as_int(pt.w)] = acc;
    }
}

__global__ void __launch_bounds__(256)
cvn_direct(const float* __restrict__ x,
           const float4* __restrict__ V16, const float4* __restrict__ V32,
           const float4* __restrict__ V64, const float4* __restrict__ V128,
           float4* __restrict__ out, int n) {
    int i = blockIdx.x * blockDim.x + threadIdx.x;
    if (i >= n) return;
    out[i] = composite(V16, V32, V64, V128, x[3 * i], x[3 * i + 1], x[3 * i + 2]);
}

extern "C" void kernel_launch(void* const* d_in, const int* in_sizes, int n_in,
                              void* d_out, int out_size, void* d_ws, size_t ws_size,
                              hipStream_t stream) {
    const float*  x    = (const float*)d_in[0];
    const float4* V16  = (const float4*)d_in[1];
    const float4* V32  = (const float4*)d_in[2];
    const float4* V64  = (const float4*)d_in[3];
    const float4* V128 = (const float4*)d_in[4];
    float4* out = (float4*)d_out;

    int n = in_sizes[0] / 3;
    int nblk = (n + PTS_PER_BLK - 1) / PTS_PER_BLK;
    int nch  = (nblk + CHUNK - 1) / CHUNK;

    auto align256 = [](size_t v) { return (v + 255) & ~(size_t)255; };
    size_t offP      = 0;
    size_t offS      = align256(offP + (size_t)nblk * NB * sizeof(int));
    size_t offSorted = align256(offS + (size_t)nch * NB * sizeof(int));
    size_t need      = offSorted + (size_t)n * sizeof(float4);

    int grid256 = (n + 255) / 256;

    if (ws_size >= need) {
        int*    P      = (int*)((char*)d_ws + offP);
        int*    S      = (int*)((char*)d_ws + offS);
        float4* sorted = (float4*)((char*)d_ws + offSorted);

        hipMemsetAsync(S, 0, (size_t)nch * NB * sizeof(int), stream);
        cvn_hist<<<nblk, H_THREADS, 0, stream>>>(x, P, S, n);
        cvn_scan_b<<<1, NB, 0, stream>>>(S, nch);
        cvn_scan_c<<<dim3(NB / 256, nch), 256, 0, stream>>>(P, S, nblk);
        cvn_scatter<<<nblk, SC_THREADS, 0, stream>>>(x, P, sorted, n);
        cvn_main4<<<NB, MT, 0, stream>>>(sorted, S, V16, V32, V64, V128,
                                         out, n);
    } else {
        cvn_direct<<<grid256, 256, 0, stream>>>(x, V16, V32, V64, V128, out, n);
    }
}

// Round 9
// 418.470 us; speedup vs baseline: 1.0038x; 1.0038x over previous
//
#include <hip/hip_runtime.h>
#include <hip/hip_fp16.h>

// CompositeValueNoise R15: controlled experiment. Base = R13 VERBATIM
// (verified 187.9us; main4 52us / 39MB F / 64MB W) -- hist, scan_a/b/c,
// scatter, launch code byte-identical. ONE change: cvn_main4 evaluates all
// four levels from LDS (V16/V32 staged fp32, clamped bucket-slice interp;
// V64/V128 fp16 as before). Isolates whether main4-side changes trigger
// the out-write amplification (R14: 752MB W) or whether that was the
// scatter rewrite (R12 evidence). Hazard watch: WRITE_SIZE >> 64MB =>
// main4-speed/write-locality theory wins; next step = tmp+permute epilogue.

#define NB 1024                // 16 x 8 x 8 buckets
#define PTS_PER_BLK 4096
#define CHUNK 32
#define SC_THREADS 1024
#define SC_PPT (PTS_PER_BLK / SC_THREADS)
#define H_THREADS 256
#define H_PPT (PTS_PER_BLK / H_THREADS)
#define MT 512                 // main kernel threads

__device__ __forceinline__ int bucket_of(float px, float py, float pz) {
    int ix = min(max((int)(px * 16.0f), 0), 15);
    int iy = min(max((int)(py * 8.0f), 0), 7);
    int iz = min(max((int)(pz * 8.0f), 0), 7);
    return (ix * 8 + iy) * 8 + iz;
}

__global__ void __launch_bounds__(H_THREADS)
cvn_hist(const float* __restrict__ x, int* __restrict__ P, int n) {
    __shared__ int cnt[NB];
    int t = threadIdx.x;
    for (int q = t; q < NB; q += H_THREADS) cnt[q] = 0;
    __syncthreads();
    int base = blockIdx.x * PTS_PER_BLK;
    for (int k = 0; k < H_PPT; ++k) {
        int i = base + k * H_THREADS + t;
        if (i < n)
            atomicAdd(&cnt[bucket_of(x[3 * i], x[3 * i + 1], x[3 * i + 2])], 1);
    }
    __syncthreads();
    int* Pb = P + (size_t)blockIdx.x * NB;
    for (int q = t; q < NB; q += H_THREADS) Pb[q] = cnt[q];
}

__global__ void __launch_bounds__(256)
cvn_scan_a(const int* __restrict__ P, int* __restrict__ S, int nblk) {
    int q = blockIdx.x * 256 + threadIdx.x;
    int c = blockIdx.y;
    int b0 = c * CHUNK, b1 = min(b0 + CHUNK, nblk);
    int s = 0;
    for (int b = b0; b < b1; ++b) s += P[(size_t)b * NB + q];
    S[(size_t)c * NB + q] = s;
}

// After: S[c][q] = Texcl[q] + exclusive chunk prefix; S[0][q] = bucket base.
// Shfl-scan version: output bit-identical to the Hillis-Steele original
// (exact integer exclusive prefix over the 1024 per-bucket totals).
__global__ void __launch_bounds__(NB)
cvn_scan_b(int* __restrict__ S, int nch) {
    __shared__ int part[16];
    int t = threadIdx.x;
    int lane = t & 63, wid = t >> 6;
    int acc = 0;
    for (int c = 0; c < nch; ++c) {
        int v = S[(size_t)c * NB + t];
        S[(size_t)c * NB + t] = acc;
        acc += v;
    }
    int sum = acc;
    #pragma unroll
    for (int off = 1; off < 64; off <<= 1) {
        int v = __shfl_up(sum, off, 64);
        if (lane >= off) sum += v;
    }
    if (lane == 63) part[wid] = sum;
    __syncthreads();
    if (t < 16) {
        int p = part[t];
        int s2 = p;
        #pragma unroll
        for (int off = 1; off < 16; off <<= 1) {
            int v = __shfl_up(s2, off, 64);
            if (t >= off) s2 += v;
        }
        part[t] = s2 - p;          // exclusive wave offset
    }
    __syncthreads();
    int texcl = part[wid] + (sum - acc);   // global exclusive prefix at t
    for (int c = 0; c < nch; ++c) S[(size_t)c * NB + t] += texcl;
}

__global__ void __launch_bounds__(256)
cvn_scan_c(int* __restrict__ P, const int* __restrict__ S, int nblk) {
    int q = blockIdx.x * 256 + threadIdx.x;
    int c = blockIdx.y;
    int b0 = c * CHUNK, b1 = min(b0 + CHUNK, nblk);
    int run = S[(size_t)c * NB + q];
    for (int b = b0; b < b1; ++b) {
        int v = P[(size_t)b * NB + q];
        P[(size_t)b * NB + q] = run;
        run += v;
    }
}

__global__ void __launch_bounds__(SC_THREADS)
cvn_scatter(const float* __restrict__ x, const int* __restrict__ P,
            float4* __restrict__ sorted, int n) {
    __shared__ int cnt[NB];
    __shared__ int place[NB];
    __shared__ int Pb[NB];
    __shared__ int sc[NB];
    __shared__ float4 payload[PTS_PER_BLK];
    __shared__ unsigned short bkt[PTS_PER_BLK];
    int t = threadIdx.x, b = blockIdx.x;
    int base = b * PTS_PER_BLK;
    cnt[t] = 0; place[t] = 0;
    Pb[t] = P[(size_t)b * NB + t];
    __syncthreads();

    float px[SC_PPT], py[SC_PPT], pz[SC_PPT];
    int qq[SC_PPT];
    #pragma unroll
    for (int k = 0; k < SC_PPT; ++k) {
        int i = base + k * SC_THREADS + t;
        if (i < n) {
            px[k] = x[3 * i]; py[k] = x[3 * i + 1]; pz[k] = x[3 * i + 2];
            qq[k] = bucket_of(px[k], py[k], pz[k]);
            atomicAdd(&cnt[qq[k]], 1);
        } else qq[k] = -1;
    }
    __syncthreads();

    sc[t] = cnt[t];
    __syncthreads();
    for (int off = 1; off < NB; off <<= 1) {
        int v = (t >= off) ? sc[t - off] : 0;
        __syncthreads();
        if (t >= off) sc[t] += v;
        __syncthreads();
    }
    cnt[t] = (t == 0) ? 0 : sc[t - 1];
    __syncthreads();

    #pragma unroll
    for (int k = 0; k < SC_PPT; ++k) {
        if (qq[k] >= 0) {
            int q = qq[k];
            int lp = atomicAdd(&place[q], 1);
            int slot = cnt[q] + lp;
            int i = base + k * SC_THREADS + t;
            payload[slot] = make_float4(px[k], py[k], pz[k], __int_as_float(i));
            bkt[slot] = (unsigned short)q;
        }
    }
    __syncthreads();

    int total = min(n - base, PTS_PER_BLK);
    #pragma unroll
    for (int k = 0; k < SC_PPT; ++k) {
        int j = k * SC_THREADS + t;
        if (j < total) {
            int q = bkt[j];
            sorted[Pb[q] + (j - cnt[q])] = payload[j];
        }
    }
}

__device__ __forceinline__ float4 lerp4(float4 a, float4 b, float w) {
    return make_float4(a.x + w * (b.x - a.x),
                       a.y + w * (b.y - a.y),
                       a.z + w * (b.z - a.z),
                       a.w + w * (b.w - a.w));
}

template <int RES>
__device__ __forceinline__ float4 level_val(const float4* __restrict__ V,
                                            float px, float py, float pz) {
    constexpr int S = RES + 1;
    float xs = fmodf(px * (float)RES, (float)RES);
    float ys = fmodf(py * (float)RES, (float)RES);
    float zs = fmodf(pz * (float)RES, (float)RES);
    float fx = floorf(xs), fy = floorf(ys), fz = floorf(zs);
    float tx = xs - fx, ty = ys - fy, tz = zs - fz;
    int ix = (int)fx, iy = (int)fy, iz = (int)fz;

    float wx = (3.0f - 2.0f * tx) * tx * tx;
    float wy = (3.0f - 2.0f * ty) * ty * ty;
    float wz = (3.0f - 2.0f * tz) * tz * tz;

    int base = (ix * S + iy) * S + iz;
    const float4* p0 = V + base;
    const float4* p1 = p0 + S * S;

    float4 c000 = p0[0];
    float4 c001 = p0[1];
    float4 c010 = p0[S];
    float4 c011 = p0[S + 1];
    float4 c100 = p1[0];
    float4 c101 = p1[1];
    float4 c110 = p1[S];
    float4 c111 = p1[S + 1];

    float4 m00 = lerp4(c000, c100, wx);
    float4 m01 = lerp4(c001, c101, wx);
    float4 m10 = lerp4(c010, c110, wx);
    float4 m11 = lerp4(c011, c111, wx);
    float4 n0  = lerp4(m00, m10, wy);
    float4 n1  = lerp4(m01, m11, wy);
    return lerp4(n0, n1, wz);
}

__device__ __forceinline__ float4 composite(const float4* __restrict__ V16,
                                            const float4* __restrict__ V32,
                                            const float4* __restrict__ V64,
                                            const float4* __restrict__ V128,
                                            float px, float py, float pz) {
    float4 acc = level_val<16>(V16, px, py, pz);
    float4 v;
    v = level_val<32>(V32, px, py, pz);
    acc.x += 0.5f * v.x; acc.y += 0.5f * v.y; acc.z += 0.5f * v.z; acc.w += 0.5f * v.w;
    v = level_val<64>(V64, px, py, pz);
    acc.x += 0.25f * v.x; acc.y += 0.25f * v.y; acc.z += 0.25f * v.z; acc.w += 0.25f * v.w;
    v = level_val<128>(V128, px, py, pz);
    acc.x += 0.125f * v.x; acc.y += 0.125f * v.y; acc.z += 0.125f * v.z; acc.w += 0.125f * v.w;
    return acc;
}

// fp16 node load: 8B (4 halves) via one ds_read_b64.
__device__ __forceinline__ float4 ldh4(const uint2* p) {
    uint2 u = *p;
    __half2 h0 = *reinterpret_cast<const __half2*>(&u.x);
    __half2 h1 = *reinterpret_cast<const __half2*>(&u.y);
    float2 f0 = __half22float2(h0);
    float2 f1 = __half22float2(h1);
    return make_float4(f0.x, f0.y, f1.x, f1.y);
}

__device__ __forceinline__ uint2 sth4(float4 v) {
    __half2 h0 = __floats2half2_rn(v.x, v.y);
    __half2 h1 = __floats2half2_rn(v.z, v.w);
    uint2 u;
    u.x = *reinterpret_cast<unsigned int*>(&h0);
    u.y = *reinterpret_cast<unsigned int*>(&h1);
    return u;
}

// Trilinear interp from an fp16 LDS slice covering one FULL coarse bucket
// (1/16 x 1/8 x 1/8). CX=RES/16 cells in x, CY=CZ=RES/8 in y/z. Clamped.
template <int RES>
__device__ __forceinline__ float4 lds_interp_h(const uint2* s,
                                               float px, float py, float pz,
                                               int ix16, int iy8, int iz8) {
    constexpr int CX = RES / 16, CY = RES / 8, CZ = RES / 8;
    constexpr int DY = CY + 1, DZ = CZ + 1;
    float xs = px * (float)RES;
    float ys = py * (float)RES;
    float zs = pz * (float)RES;
    int ixg = (int)xs, iyg = (int)ys, izg = (int)zs;
    float tx = xs - (float)ixg, ty = ys - (float)iyg, tz = zs - (float)izg;
    int lx = min(max(ixg - ix16 * CX, 0), CX - 1);
    int ly = min(max(iyg - iy8 * CY, 0), CY - 1);
    int lz = min(max(izg - iz8 * CZ, 0), CZ - 1);

    float wx = (3.0f - 2.0f * tx) * tx * tx;
    float wy = (3.0f - 2.0f * ty) * ty * ty;
    float wz = (3.0f - 2.0f * tz) * tz * tz;

    const uint2* p0 = s + (lx * DY + ly) * DZ + lz;
    const uint2* p1 = p0 + DY * DZ;
    float4 c000 = ldh4(p0),      c001 = ldh4(p0 + 1);
    float4 c010 = ldh4(p0 + DZ), c011 = ldh4(p0 + DZ + 1);
    float4 c100 = ldh4(p1),      c101 = ldh4(p1 + 1);
    float4 c110 = ldh4(p1 + DZ), c111 = ldh4(p1 + DZ + 1);

    float4 m00 = lerp4(c000, c100, wx);
    float4 m01 = lerp4(c001, c101, wx);
    float4 m10 = lerp4(c010, c110, wx);
    float4 m11 = lerp4(c011, c111, wx);
    float4 n0  = lerp4(m00, m10, wy);
    float4 n1  = lerp4(m01, m11, wy);
    return lerp4(n0, n1, wz);
}

// Same, float4 (fp32) LDS slice — for the high-weight 16/32 levels.
template <int RES>
__device__ __forceinline__ float4 lds_interp_b(const float4* s,
                                               float px, float py, float pz,
                                               int ix16, int iy8, int iz8) {
    constexpr int CX = RES / 16, CY = RES / 8, CZ = RES / 8;
    constexpr int DY = CY + 1, DZ = CZ + 1;
    float xs = px * (float)RES;
    float ys = py * (float)RES;
    float zs = pz * (float)RES;
    int ixg = (int)xs, iyg = (int)ys, izg = (int)zs;
    float tx = xs - (float)ixg, ty = ys - (float)iyg, tz = zs - (float)izg;
    int lx = min(max(ixg - ix16 * CX, 0), CX - 1);
    int ly = min(max(iyg - iy8 * CY, 0), CY - 1);
    int lz = min(max(izg - iz8 * CZ, 0), CZ - 1);

    float wx = (3.0f - 2.0f * tx) * tx * tx;
    float wy = (3.0f - 2.0f * ty) * ty * ty;
    float wz = (3.0f - 2.0f * tz) * tz * tz;

    const float4* p0 = s + (lx * DY + ly) * DZ + lz;
    const float4* p1 = p0 + DY * DZ;
    float4 c000 = p0[0],  c001 = p0[1];
    float4 c010 = p0[DZ], c011 = p0[DZ + 1];
    float4 c100 = p1[0],  c101 = p1[1];
    float4 c110 = p1[DZ], c111 = p1[DZ + 1];

    float4 m00 = lerp4(c000, c100, wx);
    float4 m01 = lerp4(c001, c101, wx);
    float4 m10 = lerp4(c010, c110, wx);
    float4 m11 = lerp4(c011, c111, wx);
    float4 n0  = lerp4(m00, m10, wy);
    float4 n1  = lerp4(m01, m11, wy);
    return lerp4(n0, n1, wz);
}

// One WG per 1/16x1/8x1/8 bucket. ALL levels staged to LDS: V64/V128 fp16
// (24KB), V16/V32 float4 (1.5KB). Point loop: coalesced sorted read,
// LDS-only eval, scattered out[orig] write (idx in .w).
__global__ void __launch_bounds__(MT, 8)
cvn_main4(const float4* __restrict__ sorted, const int* __restrict__ Tbase,
          const float4* __restrict__ V16, const float4* __restrict__ V32,
          const float4* __restrict__ V64, const float4* __restrict__ V128,
          float4* __restrict__ out, int n) {
    __shared__ uint2 s128[9 * 17 * 17];   // 2601 -> 20808 B
    __shared__ uint2 s64[5 * 9 * 9];      //  405 ->  3240 B
    __shared__ float4 s32f[3 * 5 * 5];    //   75 ->  1200 B
    __shared__ float4 s16f[2 * 3 * 3];    //   18 ->   288 B
    int t = threadIdx.x, b = blockIdx.x;

    // XCD-compact mapping: b&7 -> octant of the 16x8x8 bucket space
    // (8x4x4 buckets each); g enumerated x-slowest so the ~64 resident
    // buckets per XCD form a compact region (~2.2 MB V128 slice < 4MB L2).
    int ox = b & 1, oy = (b >> 1) & 1, oz = (b >> 2) & 1;
    int g  = b >> 3;                         // 0..127
    int gx = g >> 4, gy = (g >> 2) & 3, gz = g & 3;
    int ix16 = ox * 8 + gx, iy8 = oy * 4 + gy, iz8 = oz * 4 + gz;
    int q = (ix16 * 8 + iy8) * 8 + iz8;

    int base = Tbase[q];
    int end  = (q == NB - 1) ? n : Tbase[q + 1];
    int len  = end - base;

    // Stage: V128 9x17x17 fp16, V64 5x9x9 fp16, V32 3x5x5 f32, V16 2x3x3 f32.
    int bx = ix16 * 8, by = iy8 * 16, bz = iz8 * 16;
    for (int u = t; u < 2601; u += MT) {
        int a = u / 289, r = u - a * 289;
        int bb = r / 17, c = r - bb * 17;
        s128[u] = sth4(V128[((size_t)(bx + a) * 129 + (by + bb)) * 129
                            + (bz + c)]);
    }
    for (int u = t; u < 405; u += MT) {
        int a = u / 81, r = u - a * 81;
        int bb = r / 9, c = r - bb * 9;
        s64[u] = sth4(V64[((size_t)(ix16 * 4 + a) * 65 + (iy8 * 8 + bb)) * 65
                          + (iz8 * 8 + c)]);
    }
    for (int u = t; u < 75; u += MT) {
        int a = u / 25, r = u - a * 25;
        int bb = r / 5, c = r - bb * 5;
        s32f[u] = V32[((size_t)(ix16 * 2 + a) * 33 + (iy8 * 4 + bb)) * 33
                      + (iz8 * 4 + c)];
    }
    for (int u = t; u < 18; u += MT) {
        int a = u / 9, r = u - a * 9;
        int bb = r / 3, c = r - bb * 3;
        s16f[u] = V16[((size_t)(ix16 + a) * 17 + (iy8 * 2 + bb)) * 17
                      + (iz8 * 2 + c)];
    }
    __syncthreads();

    // Stream points: coalesced read; all levels via LDS; scattered out write.
    for (int p = t; p < len; p += MT) {
        float4 pt = sorted[base + p];
        float4 acc = lds_interp_b<16>(s16f, pt.x, pt.y, pt.z, ix16, iy8, iz8);
        float4 v;
        v = lds_interp_b<32>(s32f, pt.x, pt.y, pt.z, ix16, iy8, iz8);
        acc.x += 0.5f * v.x; acc.y += 0.5f * v.y;
        acc.z += 0.5f * v.z; acc.w += 0.5f * v.w;
        v = lds_interp_h<64>(s64, pt.x, pt.y, pt.z, ix16, iy8, iz8);
        acc.x += 0.25f * v.x; acc.y += 0.25f * v.y;
        acc.z += 0.25f * v.z; acc.w += 0.25f * v.w;
        v = lds_interp_h<128>(s128, pt.x, pt.y, pt.z, ix16, iy8, iz8);
        acc.x += 0.125f * v.x; acc.y += 0.125f * v.y;
        acc.z += 0.125f * v.z; acc.w += 0.125f * v.w;
        out[__float_as_int(pt.w)] = acc;
    }
}

__global__ void __launch_bounds__(256)
cvn_direct(const float* __restrict__ x,
           const float4* __restrict__ V16, const float4* __restrict__ V32,
           const float4* __restrict__ V64, const float4* __restrict__ V128,
           float4* __restrict__ out, int n) {
    int i = blockIdx.x * blockDim.x + threadIdx.x;
    if (i >= n) return;
    out[i] = composite(V16, V32, V64, V128, x[3 * i], x[3 * i + 1], x[3 * i + 2]);
}

extern "C" void kernel_launch(void* const* d_in, const int* in_sizes, int n_in,
                              void* d_out, int out_size, void* d_ws, size_t ws_size,
                              hipStream_t stream) {
    const float*  x    = (const float*)d_in[0];
    const float4* V16  = (const float4*)d_in[1];
    const float4* V32  = (const float4*)d_in[2];
    const float4* V64  = (const float4*)d_in[3];
    const float4* V128 = (const float4*)d_in[4];
    float4* out = (float4*)d_out;

    int n = in_sizes[0] / 3;
    int nblk = (n + PTS_PER_BLK - 1) / PTS_PER_BLK;
    int nch  = (nblk + CHUNK - 1) / CHUNK;

    auto align256 = [](size_t v) { return (v + 255) & ~(size_t)255; };
    size_t offP      = 0;
    size_t offS      = align256(offP + (size_t)nblk * NB * sizeof(int));
    size_t offSorted = align256(offS + (size_t)nch * NB * sizeof(int));
    size_t need      = offSorted + (size_t)n * sizeof(float4);

    int grid256 = (n + 255) / 256;

    if (ws_size >= need) {
        int*    P      = (int*)((char*)d_ws + offP);
        int*    S      = (int*)((char*)d_ws + offS);
        float4* sorted = (float4*)((char*)d_ws + offSorted);

        cvn_hist<<<nblk, H_THREADS, 0, stream>>>(x, P, n);
        cvn_scan_a<<<dim3(NB / 256, nch), 256, 0, stream>>>(P, S, nblk);
        cvn_scan_b<<<1, NB, 0, stream>>>(S, nch);
        cvn_scan_c<<<dim3(NB / 256, nch), 256, 0, stream>>>(P, S, nblk);
        cvn_scatter<<<nblk, SC_THREADS, 0, stream>>>(x, P, sorted, n);
        cvn_main4<<<NB, MT, 0, stream>>>(sorted, S, V16, V32, V64, V128,
                                         out, n);
    } else {
        cvn_direct<<<grid256, 256, 0, stream>>>(x, V16, V32, V64, V128, out, n);
    }
}

// Round 10
// 324.331 us; speedup vs baseline: 1.2952x; 1.2903x over previous
//
#include <hip/hip_runtime.h>
#include <hip/hip_fp16.h>

// CompositeValueNoise R16: robust-structure rebuild. Evidence from R11-R15:
// main4's scattered out[orig] write is bimodal under a CODEGEN LOTTERY
// (SGPR 48 vs 64 tracks bad vs good perfectly; same source can compile
// either way depending on unrelated module contents; bad mode = 752MB W).
// Fix: NO scattered global writes anywhere hot. main4 writes tmp[] fully
// coalesced; permute epilogue out[i] = tmp[rank[i]] (L3-served gather,
// ~33us measured in R9). With fragility gone, the previously-poisoned
// optimizations are applied safely together:
//  - main4: all-LDS eval (V64/V128 fp16, V16/V32 fp32), coalesced tmp write
//  - hist: fused chunk-sum accumulation (scan_a deleted; bit-identical S)
//  - scatter: 2-barrier shfl scan, q packed in payload.w (78KB LDS,
//    2 blocks/CU), rank[] written coalesced
// Robustness check: main4 WRITE_SIZE must stay ~35MB.

#define NB 1024                // 16 x 8 x 8 buckets
#define PTS_PER_BLK 4096
#define CHUNK 32
#define SC_THREADS 1024
#define SC_PPT (PTS_PER_BLK / SC_THREADS)
#define H_THREADS 256
#define H_PPT (PTS_PER_BLK / H_THREADS)
#define MT 512                 // main kernel threads
#define IDXMASK 0x1FFFFF       // n < 2^21

__device__ __forceinline__ int bucket_of(float px, float py, float pz) {
    int ix = min(max((int)(px * 16.0f), 0), 15);
    int iy = min(max((int)(py * 8.0f), 0), 7);
    int iz = min(max((int)(pz * 8.0f), 0), 7);
    return (ix * 8 + iy) * 8 + iz;
}

// Per-block counts -> P[b][q]; chunk sums accumulated into S[c][q]
// (S pre-zeroed; integer atomic adds -> bit-identical to old scan_a).
__global__ void __launch_bounds__(H_THREADS)
cvn_hist(const float* __restrict__ x, int* __restrict__ P,
         int* __restrict__ S, int n) {
    __shared__ int cnt[NB];
    int t = threadIdx.x;
    for (int q = t; q < NB; q += H_THREADS) cnt[q] = 0;
    __syncthreads();
    int base = blockIdx.x * PTS_PER_BLK;
    for (int k = 0; k < H_PPT; ++k) {
        int i = base + k * H_THREADS + t;
        if (i < n)
            atomicAdd(&cnt[bucket_of(x[3 * i], x[3 * i + 1], x[3 * i + 2])], 1);
    }
    __syncthreads();
    int* Pb = P + (size_t)blockIdx.x * NB;
    int* Sc = S + (size_t)(blockIdx.x / CHUNK) * NB;
    for (int q = t; q < NB; q += H_THREADS) {
        int v = cnt[q];
        Pb[q] = v;
        if (v) atomicAdd(&Sc[q], v);
    }
}

// After: S[c][q] = Texcl[q] + exclusive chunk prefix; S[0][q] = bucket base.
__global__ void __launch_bounds__(NB)
cvn_scan_b(int* __restrict__ S, int nch) {
    __shared__ int part[16];
    int t = threadIdx.x;
    int lane = t & 63, wid = t >> 6;
    int acc = 0;
    for (int c = 0; c < nch; ++c) {
        int v = S[(size_t)c * NB + t];
        S[(size_t)c * NB + t] = acc;
        acc += v;
    }
    int sum = acc;
    #pragma unroll
    for (int off = 1; off < 64; off <<= 1) {
        int v = __shfl_up(sum, off, 64);
        if (lane >= off) sum += v;
    }
    if (lane == 63) part[wid] = sum;
    __syncthreads();
    if (t < 16) {
        int p = part[t];
        int s2 = p;
        #pragma unroll
        for (int off = 1; off < 16; off <<= 1) {
            int v = __shfl_up(s2, off, 64);
            if (t >= off) s2 += v;
        }
        part[t] = s2 - p;          // exclusive wave offset
    }
    __syncthreads();
    int texcl = part[wid] + (sum - acc);   // global exclusive prefix at t
    for (int c = 0; c < nch; ++c) S[(size_t)c * NB + t] += texcl;
}

__global__ void __launch_bounds__(256)
cvn_scan_c(int* __restrict__ P, const int* __restrict__ S, int nblk) {
    int q = blockIdx.x * 256 + threadIdx.x;
    int c = blockIdx.y;
    int b0 = c * CHUNK, b1 = min(b0 + CHUNK, nblk);
    int run = S[(size_t)c * NB + q];
    for (int b = b0; b < b1; ++b) {
        int v = P[(size_t)b * NB + q];
        P[(size_t)b * NB + q] = run;
        run += v;
    }
}

// Deterministic (stable) scatter; q packed into payload.w; 2-barrier scan;
// rank[i] (final sorted position of point i) written coalesced in i.
__global__ void __launch_bounds__(SC_THREADS, 8)
cvn_scatter(const float* __restrict__ x, const int* __restrict__ P,
            float4* __restrict__ sorted, int* __restrict__ rank, int n) {
    __shared__ int cnt[NB];       //  counts -> exclusive staging starts
    __shared__ int place[NB];
    __shared__ int Pb[NB];
    __shared__ int part[16];
    __shared__ float4 payload[PTS_PER_BLK];   // 64KB
    int t = threadIdx.x, b = blockIdx.x;
    int lane = t & 63, wid = t >> 6;
    int base = b * PTS_PER_BLK;
    cnt[t] = 0; place[t] = 0;
    Pb[t] = P[(size_t)b * NB + t];
    __syncthreads();

    float px[SC_PPT], py[SC_PPT], pz[SC_PPT];
    int qq[SC_PPT];
    #pragma unroll
    for (int k = 0; k < SC_PPT; ++k) {
        int i = base + k * SC_THREADS + t;
        if (i < n) {
            px[k] = x[3 * i]; py[k] = x[3 * i + 1]; pz[k] = x[3 * i + 2];
            qq[k] = bucket_of(px[k], py[k], pz[k]);
            atomicAdd(&cnt[qq[k]], 1);
        } else qq[k] = -1;
    }
    __syncthreads();

    // Exclusive scan of cnt[1024]: per-wave shfl scan + 16-partial scan.
    int c0 = cnt[t];
    int sum = c0;
    #pragma unroll
    for (int off = 1; off < 64; off <<= 1) {
        int v = __shfl_up(sum, off, 64);
        if (lane >= off) sum += v;
    }
    if (lane == 63) part[wid] = sum;
    __syncthreads();
    if (t < 16) {
        int p = part[t];
        int s2 = p;
        #pragma unroll
        for (int off = 1; off < 16; off <<= 1) {
            int v = __shfl_up(s2, off, 64);
            if (t >= off) s2 += v;
        }
        part[t] = s2 - p;          // exclusive wave offset
    }
    __syncthreads();
    cnt[t] = part[wid] + (sum - c0);   // exclusive staging start
    __syncthreads();

    #pragma unroll
    for (int k = 0; k < SC_PPT; ++k) {
        if (qq[k] >= 0) {
            int q = qq[k];
            int lp = atomicAdd(&place[q], 1);
            int slot = cnt[q] + lp;
            int i = base + k * SC_THREADS + t;
            payload[slot] = make_float4(px[k], py[k], pz[k],
                                        __int_as_float(i | (q << 21)));
            rank[i] = Pb[q] + lp;      // coalesced in i
        }
    }
    __syncthreads();

    int total = min(n - base, PTS_PER_BLK);
    #pragma unroll
    for (int k = 0; k < SC_PPT; ++k) {
        int j = k * SC_THREADS + t;
        if (j < total) {
            float4 pl = payload[j];
            int w = __float_as_int(pl.w);
            int q = w >> 21;
            pl.w = __int_as_float(w & IDXMASK);
            sorted[Pb[q] + (j - cnt[q])] = pl;
        }
    }
}

__device__ __forceinline__ float4 lerp4(float4 a, float4 b, float w) {
    return make_float4(a.x + w * (b.x - a.x),
                       a.y + w * (b.y - a.y),
                       a.z + w * (b.z - a.z),
                       a.w + w * (b.w - a.w));
}

template <int RES>
__device__ __forceinline__ float4 level_val(const float4* __restrict__ V,
                                            float px, float py, float pz) {
    constexpr int S = RES + 1;
    float xs = fmodf(px * (float)RES, (float)RES);
    float ys = fmodf(py * (float)RES, (float)RES);
    float zs = fmodf(pz * (float)RES, (float)RES);
    float fx = floorf(xs), fy = floorf(ys), fz = floorf(zs);
    float tx = xs - fx, ty = ys - fy, tz = zs - fz;
    int ix = (int)fx, iy = (int)fy, iz = (int)fz;

    float wx = (3.0f - 2.0f * tx) * tx * tx;
    float wy = (3.0f - 2.0f * ty) * ty * ty;
    float wz = (3.0f - 2.0f * tz) * tz * tz;

    int base = (ix * S + iy) * S + iz;
    const float4* p0 = V + base;
    const float4* p1 = p0 + S * S;

    float4 c000 = p0[0];
    float4 c001 = p0[1];
    float4 c010 = p0[S];
    float4 c011 = p0[S + 1];
    float4 c100 = p1[0];
    float4 c101 = p1[1];
    float4 c110 = p1[S];
    float4 c111 = p1[S + 1];

    float4 m00 = lerp4(c000, c100, wx);
    float4 m01 = lerp4(c001, c101, wx);
    float4 m10 = lerp4(c010, c110, wx);
    float4 m11 = lerp4(c011, c111, wx);
    float4 n0  = lerp4(m00, m10, wy);
    float4 n1  = lerp4(m01, m11, wy);
    return lerp4(n0, n1, wz);
}

__device__ __forceinline__ float4 composite(const float4* __restrict__ V16,
                                            const float4* __restrict__ V32,
                                            const float4* __restrict__ V64,
                                            const float4* __restrict__ V128,
                                            float px, float py, float pz) {
    float4 acc = level_val<16>(V16, px, py, pz);
    float4 v;
    v = level_val<32>(V32, px, py, pz);
    acc.x += 0.5f * v.x; acc.y += 0.5f * v.y; acc.z += 0.5f * v.z; acc.w += 0.5f * v.w;
    v = level_val<64>(V64, px, py, pz);
    acc.x += 0.25f * v.x; acc.y += 0.25f * v.y; acc.z += 0.25f * v.z; acc.w += 0.25f * v.w;
    v = level_val<128>(V128, px, py, pz);
    acc.x += 0.125f * v.x; acc.y += 0.125f * v.y; acc.z += 0.125f * v.z; acc.w += 0.125f * v.w;
    return acc;
}

// fp16 node load: 8B (4 halves) via one ds_read_b64.
__device__ __forceinline__ float4 ldh4(const uint2* p) {
    uint2 u = *p;
    __half2 h0 = *reinterpret_cast<const __half2*>(&u.x);
    __half2 h1 = *reinterpret_cast<const __half2*>(&u.y);
    float2 f0 = __half22float2(h0);
    float2 f1 = __half22float2(h1);
    return make_float4(f0.x, f0.y, f1.x, f1.y);
}

__device__ __forceinline__ uint2 sth4(float4 v) {
    __half2 h0 = __floats2half2_rn(v.x, v.y);
    __half2 h1 = __floats2half2_rn(v.z, v.w);
    uint2 u;
    u.x = *reinterpret_cast<unsigned int*>(&h0);
    u.y = *reinterpret_cast<unsigned int*>(&h1);
    return u;
}

// Trilinear interp from an fp16 LDS slice covering one FULL coarse bucket
// (1/16 x 1/8 x 1/8). CX=RES/16 cells in x, CY=CZ=RES/8 in y/z. Clamped.
template <int RES>
__device__ __forceinline__ float4 lds_interp_h(const uint2* s,
                                               float px, float py, float pz,
                                               int ix16, int iy8, int iz8) {
    constexpr int CX = RES / 16, CY = RES / 8, CZ = RES / 8;
    constexpr int DY = CY + 1, DZ = CZ + 1;
    float xs = px * (float)RES;
    float ys = py * (float)RES;
    float zs = pz * (float)RES;
    int ixg = (int)xs, iyg = (int)ys, izg = (int)zs;
    float tx = xs - (float)ixg, ty = ys - (float)iyg, tz = zs - (float)izg;
    int lx = min(max(ixg - ix16 * CX, 0), CX - 1);
    int ly = min(max(iyg - iy8 * CY, 0), CY - 1);
    int lz = min(max(izg - iz8 * CZ, 0), CZ - 1);

    float wx = (3.0f - 2.0f * tx) * tx * tx;
    float wy = (3.0f - 2.0f * ty) * ty * ty;
    float wz = (3.0f - 2.0f * tz) * tz * tz;

    const uint2* p0 = s + (lx * DY + ly) * DZ + lz;
    const uint2* p1 = p0 + DY * DZ;
    float4 c000 = ldh4(p0),      c001 = ldh4(p0 + 1);
    float4 c010 = ldh4(p0 + DZ), c011 = ldh4(p0 + DZ + 1);
    float4 c100 = ldh4(p1),      c101 = ldh4(p1 + 1);
    float4 c110 = ldh4(p1 + DZ), c111 = ldh4(p1 + DZ + 1);

    float4 m00 = lerp4(c000, c100, wx);
    float4 m01 = lerp4(c001, c101, wx);
    float4 m10 = lerp4(c010, c110, wx);
    float4 m11 = lerp4(c011, c111, wx);
    float4 n0  = lerp4(m00, m10, wy);
    float4 n1  = lerp4(m01, m11, wy);
    return lerp4(n0, n1, wz);
}

// Same, float4 (fp32) LDS slice — for the high-weight 16/32 levels.
template <int RES>
__device__ __forceinline__ float4 lds_interp_b(const float4* s,
                                               float px, float py, float pz,
                                               int ix16, int iy8, int iz8) {
    constexpr int CX = RES / 16, CY = RES / 8, CZ = RES / 8;
    constexpr int DY = CY + 1, DZ = CZ + 1;
    float xs = px * (float)RES;
    float ys = py * (float)RES;
    float zs = pz * (float)RES;
    int ixg = (int)xs, iyg = (int)ys, izg = (int)zs;
    float tx = xs - (float)ixg, ty = ys - (float)iyg, tz = zs - (float)izg;
    int lx = min(max(ixg - ix16 * CX, 0), CX - 1);
    int ly = min(max(iyg - iy8 * CY, 0), CY - 1);
    int lz = min(max(izg - iz8 * CZ, 0), CZ - 1);

    float wx = (3.0f - 2.0f * tx) * tx * tx;
    float wy = (3.0f - 2.0f * ty) * ty * ty;
    float wz = (3.0f - 2.0f * tz) * tz * tz;

    const float4* p0 = s + (lx * DY + ly) * DZ + lz;
    const float4* p1 = p0 + DY * DZ;
    float4 c000 = p0[0],  c001 = p0[1];
    float4 c010 = p0[DZ], c011 = p0[DZ + 1];
    float4 c100 = p1[0],  c101 = p1[1];
    float4 c110 = p1[DZ], c111 = p1[DZ + 1];

    float4 m00 = lerp4(c000, c100, wx);
    float4 m01 = lerp4(c001, c101, wx);
    float4 m10 = lerp4(c010, c110, wx);
    float4 m11 = lerp4(c011, c111, wx);
    float4 n0  = lerp4(m00, m10, wy);
    float4 n1  = lerp4(m01, m11, wy);
    return lerp4(n0, n1, wz);
}

// One WG per 1/16x1/8x1/8 bucket. ALL levels staged to LDS. Point loop:
// coalesced sorted read, LDS-only eval, COALESCED tmp write (no scattered
// global writes -> immune to the codegen lottery).
__global__ void __launch_bounds__(MT, 8)
cvn_main4(const float4* __restrict__ sorted, const int* __restrict__ Tbase,
          const float4* __restrict__ V16, const float4* __restrict__ V32,
          const float4* __restrict__ V64, const float4* __restrict__ V128,
          float4* __restrict__ tmp, int n) {
    __shared__ uint2 s128[9 * 17 * 17];   // 2601 -> 20808 B
    __shared__ uint2 s64[5 * 9 * 9];      //  405 ->  3240 B
    __shared__ float4 s32f[3 * 5 * 5];    //   75 ->  1200 B
    __shared__ float4 s16f[2 * 3 * 3];    //   18 ->   288 B
    int t = threadIdx.x, b = blockIdx.x;

    // XCD-compact mapping: b&7 -> octant of the 16x8x8 bucket space.
    int ox = b & 1, oy = (b >> 1) & 1, oz = (b >> 2) & 1;
    int g  = b >> 3;                         // 0..127
    int gx = g >> 4, gy = (g >> 2) & 3, gz = g & 3;
    int ix16 = ox * 8 + gx, iy8 = oy * 4 + gy, iz8 = oz * 4 + gz;
    int q = (ix16 * 8 + iy8) * 8 + iz8;

    int base = Tbase[q];
    int end  = (q == NB - 1) ? n : Tbase[q + 1];
    int len  = end - base;

    // Stage: V128 9x17x17 fp16, V64 5x9x9 fp16, V32 3x5x5 f32, V16 2x3x3 f32.
    int bx = ix16 * 8, by = iy8 * 16, bz = iz8 * 16;
    for (int u = t; u < 2601; u += MT) {
        int a = u / 289, r = u - a * 289;
        int bb = r / 17, c = r - bb * 17;
        s128[u] = sth4(V128[((size_t)(bx + a) * 129 + (by + bb)) * 129
                            + (bz + c)]);
    }
    for (int u = t; u < 405; u += MT) {
        int a = u / 81, r = u - a * 81;
        int bb = r / 9, c = r - bb * 9;
        s64[u] = sth4(V64[((size_t)(ix16 * 4 + a) * 65 + (iy8 * 8 + bb)) * 65
                          + (iz8 * 8 + c)]);
    }
    for (int u = t; u < 75; u += MT) {
        int a = u / 25, r = u - a * 25;
        int bb = r / 5, c = r - bb * 5;
        s32f[u] = V32[((size_t)(ix16 * 2 + a) * 33 + (iy8 * 4 + bb)) * 33
                      + (iz8 * 4 + c)];
    }
    for (int u = t; u < 18; u += MT) {
        int a = u / 9, r = u - a * 9;
        int bb = r / 3, c = r - bb * 3;
        s16f[u] = V16[((size_t)(ix16 + a) * 17 + (iy8 * 2 + bb)) * 17
                      + (iz8 * 2 + c)];
    }
    __syncthreads();

    // Stream points: coalesced read, LDS-only eval, coalesced tmp write.
    for (int p = t; p < len; p += MT) {
        float4 pt = sorted[base + p];
        float4 acc = lds_interp_b<16>(s16f, pt.x, pt.y, pt.z, ix16, iy8, iz8);
        float4 v;
        v = lds_interp_b<32>(s32f, pt.x, pt.y, pt.z, ix16, iy8, iz8);
        acc.x += 0.5f * v.x; acc.y += 0.5f * v.y;
        acc.z += 0.5f * v.z; acc.w += 0.5f * v.w;
        v = lds_interp_h<64>(s64, pt.x, pt.y, pt.z, ix16, iy8, iz8);
        acc.x += 0.25f * v.x; acc.y += 0.25f * v.y;
        acc.z += 0.25f * v.z; acc.w += 0.25f * v.w;
        v = lds_interp_h<128>(s128, pt.x, pt.y, pt.z, ix16, iy8, iz8);
        acc.x += 0.125f * v.x; acc.y += 0.125f * v.y;
        acc.z += 0.125f * v.z; acc.w += 0.125f * v.w;
        acc.w = acc.w;   // .w carries field 3 (orig idx no longer needed)
        tmp[base + p] = acc;
    }
}

// Gather epilogue: out[i] = tmp[rank[i]] (rank coalesced; tmp via L3).
__global__ void __launch_bounds__(256)
cvn_permute(const float4* __restrict__ tmp, const int* __restrict__ rank,
            float4* __restrict__ out, int n) {
    int i = blockIdx.x * 256 + (int)threadIdx.x;
    if (i >= n) return;
    out[i] = tmp[rank[i]];
}

__global__ void __launch_bounds__(256)
cvn_direct(const float* __restrict__ x,
           const float4* __restrict__ V16, const float4* __restrict__ V32,
           const float4* __restrict__ V64, const float4* __restrict__ V128,
           float4* __restrict__ out, int n) {
    int i = blockIdx.x * blockDim.x + threadIdx.x;
    if (i >= n) return;
    out[i] = composite(V16, V32, V64, V128, x[3 * i], x[3 * i + 1], x[3 * i + 2]);
}

extern "C" void kernel_launch(void* const* d_in, const int* in_sizes, int n_in,
                              void* d_out, int out_size, void* d_ws, size_t ws_size,
                              hipStream_t stream) {
    const float*  x    = (const float*)d_in[0];
    const float4* V16  = (const float4*)d_in[1];
    const float4* V32  = (const float4*)d_in[2];
    const float4* V64  = (const float4*)d_in[3];
    const float4* V128 = (const float4*)d_in[4];
    float4* out = (float4*)d_out;

    int n = in_sizes[0] / 3;
    int nblk = (n + PTS_PER_BLK - 1) / PTS_PER_BLK;
    int nch  = (nblk + CHUNK - 1) / CHUNK;

    auto align256 = [](size_t v) { return (v + 255) & ~(size_t)255; };
    size_t offP      = 0;
    size_t offS      = align256(offP + (size_t)nblk * NB * sizeof(int));
    size_t offSorted = align256(offS + (size_t)nch * NB * sizeof(int));
    size_t offRank   = align256(offSorted + (size_t)n * sizeof(float4));
    size_t offTmp    = align256(offRank + (size_t)n * sizeof(int));
    size_t need      = offTmp + (size_t)n * sizeof(float4);

    int grid256 = (n + 255) / 256;

    if (ws_size >= need) {
        int*    P      = (int*)((char*)d_ws + offP);
        int*    S      = (int*)((char*)d_ws + offS);
        float4* sorted = (float4*)((char*)d_ws + offSorted);
        int*    rank   = (int*)((char*)d_ws + offRank);
        float4* tmp    = (float4*)((char*)d_ws + offTmp);

        hipMemsetAsync(S, 0, (size_t)nch * NB * sizeof(int), stream);
        cvn_hist<<<nblk, H_THREADS, 0, stream>>>(x, P, S, n);
        cvn_scan_b<<<1, NB, 0, stream>>>(S, nch);
        cvn_scan_c<<<dim3(NB / 256, nch), 256, 0, stream>>>(P, S, nblk);
        cvn_scatter<<<nblk, SC_THREADS, 0, stream>>>(x, P, sorted, rank, n);
        cvn_main4<<<NB, MT, 0, stream>>>(sorted, S, V16, V32, V64, V128,
                                         tmp, n);
        cvn_permute<<<grid256, 256, 0, stream>>>(tmp, rank, out, n);
    } else {
        cvn_direct<<<grid256, 256, 0, stream>>>(x, V16, V32, V64, V128, out, n);
    }
}

// Round 11
// 206.489 us; speedup vs baseline: 2.0344x; 1.5707x over previous
//
#include <hip/hip_runtime.h>
#include <hip/hip_fp16.h>

// CompositeValueNoise R17: single-variable spill test. Base = R16 VERBATIM
// except cvn_main4 launch_bounds (512,8)->(512,4) (VGPR cap 64->128).
// Theory (fits ALL rounds): all-LDS eval exceeds 64-VGPR cap -> per-point
// scratch spill traffic (R16: coalesced tmp write yet 164MB F / 335MB W;
// scratch is the only other memory client). R12's "identical source" bad
// round = co-compiled kernels sharing regalloc context (SGPR 48/64 flip).
// Scattered-write amplification was a secondary effect of spill pacing.
// Prediction: main4 FETCH ~55MB, WRITE ~35MB, dur ~35us, VGPR>64 reported.

#define NB 1024                // 16 x 8 x 8 buckets
#define PTS_PER_BLK 4096
#define CHUNK 32
#define SC_THREADS 1024
#define SC_PPT (PTS_PER_BLK / SC_THREADS)
#define H_THREADS 256
#define H_PPT (PTS_PER_BLK / H_THREADS)
#define MT 512                 // main kernel threads
#define IDXMASK 0x1FFFFF       // n < 2^21

__device__ __forceinline__ int bucket_of(float px, float py, float pz) {
    int ix = min(max((int)(px * 16.0f), 0), 15);
    int iy = min(max((int)(py * 8.0f), 0), 7);
    int iz = min(max((int)(pz * 8.0f), 0), 7);
    return (ix * 8 + iy) * 8 + iz;
}

// Per-block counts -> P[b][q]; chunk sums accumulated into S[c][q]
// (S pre-zeroed; integer atomic adds -> bit-identical to old scan_a).
__global__ void __launch_bounds__(H_THREADS)
cvn_hist(const float* __restrict__ x, int* __restrict__ P,
         int* __restrict__ S, int n) {
    __shared__ int cnt[NB];
    int t = threadIdx.x;
    for (int q = t; q < NB; q += H_THREADS) cnt[q] = 0;
    __syncthreads();
    int base = blockIdx.x * PTS_PER_BLK;
    for (int k = 0; k < H_PPT; ++k) {
        int i = base + k * H_THREADS + t;
        if (i < n)
            atomicAdd(&cnt[bucket_of(x[3 * i], x[3 * i + 1], x[3 * i + 2])], 1);
    }
    __syncthreads();
    int* Pb = P + (size_t)blockIdx.x * NB;
    int* Sc = S + (size_t)(blockIdx.x / CHUNK) * NB;
    for (int q = t; q < NB; q += H_THREADS) {
        int v = cnt[q];
        Pb[q] = v;
        if (v) atomicAdd(&Sc[q], v);
    }
}

// After: S[c][q] = Texcl[q] + exclusive chunk prefix; S[0][q] = bucket base.
__global__ void __launch_bounds__(NB)
cvn_scan_b(int* __restrict__ S, int nch) {
    __shared__ int part[16];
    int t = threadIdx.x;
    int lane = t & 63, wid = t >> 6;
    int acc = 0;
    for (int c = 0; c < nch; ++c) {
        int v = S[(size_t)c * NB + t];
        S[(size_t)c * NB + t] = acc;
        acc += v;
    }
    int sum = acc;
    #pragma unroll
    for (int off = 1; off < 64; off <<= 1) {
        int v = __shfl_up(sum, off, 64);
        if (lane >= off) sum += v;
    }
    if (lane == 63) part[wid] = sum;
    __syncthreads();
    if (t < 16) {
        int p = part[t];
        int s2 = p;
        #pragma unroll
        for (int off = 1; off < 16; off <<= 1) {
            int v = __shfl_up(s2, off, 64);
            if (t >= off) s2 += v;
        }
        part[t] = s2 - p;          // exclusive wave offset
    }
    __syncthreads();
    int texcl = part[wid] + (sum - acc);   // global exclusive prefix at t
    for (int c = 0; c < nch; ++c) S[(size_t)c * NB + t] += texcl;
}

__global__ void __launch_bounds__(256)
cvn_scan_c(int* __restrict__ P, const int* __restrict__ S, int nblk) {
    int q = blockIdx.x * 256 + threadIdx.x;
    int c = blockIdx.y;
    int b0 = c * CHUNK, b1 = min(b0 + CHUNK, nblk);
    int run = S[(size_t)c * NB + q];
    for (int b = b0; b < b1; ++b) {
        int v = P[(size_t)b * NB + q];
        P[(size_t)b * NB + q] = run;
        run += v;
    }
}

// Deterministic (stable) scatter; q packed into payload.w; 2-barrier scan;
// rank[i] (final sorted position of point i) written coalesced in i.
__global__ void __launch_bounds__(SC_THREADS, 8)
cvn_scatter(const float* __restrict__ x, const int* __restrict__ P,
            float4* __restrict__ sorted, int* __restrict__ rank, int n) {
    __shared__ int cnt[NB];       //  counts -> exclusive staging starts
    __shared__ int place[NB];
    __shared__ int Pb[NB];
    __shared__ int part[16];
    __shared__ float4 payload[PTS_PER_BLK];   // 64KB
    int t = threadIdx.x, b = blockIdx.x;
    int lane = t & 63, wid = t >> 6;
    int base = b * PTS_PER_BLK;
    cnt[t] = 0; place[t] = 0;
    Pb[t] = P[(size_t)b * NB + t];
    __syncthreads();

    float px[SC_PPT], py[SC_PPT], pz[SC_PPT];
    int qq[SC_PPT];
    #pragma unroll
    for (int k = 0; k < SC_PPT; ++k) {
        int i = base + k * SC_THREADS + t;
        if (i < n) {
            px[k] = x[3 * i]; py[k] = x[3 * i + 1]; pz[k] = x[3 * i + 2];
            qq[k] = bucket_of(px[k], py[k], pz[k]);
            atomicAdd(&cnt[qq[k]], 1);
        } else qq[k] = -1;
    }
    __syncthreads();

    // Exclusive scan of cnt[1024]: per-wave shfl scan + 16-partial scan.
    int c0 = cnt[t];
    int sum = c0;
    #pragma unroll
    for (int off = 1; off < 64; off <<= 1) {
        int v = __shfl_up(sum, off, 64);
        if (lane >= off) sum += v;
    }
    if (lane == 63) part[wid] = sum;
    __syncthreads();
    if (t < 16) {
        int p = part[t];
        int s2 = p;
        #pragma unroll
        for (int off = 1; off < 16; off <<= 1) {
            int v = __shfl_up(s2, off, 64);
            if (t >= off) s2 += v;
        }
        part[t] = s2 - p;          // exclusive wave offset
    }
    __syncthreads();
    cnt[t] = part[wid] + (sum - c0);   // exclusive staging start
    __syncthreads();

    #pragma unroll
    for (int k = 0; k < SC_PPT; ++k) {
        if (qq[k] >= 0) {
            int q = qq[k];
            int lp = atomicAdd(&place[q], 1);
            int slot = cnt[q] + lp;
            int i = base + k * SC_THREADS + t;
            payload[slot] = make_float4(px[k], py[k], pz[k],
                                        __int_as_float(i | (q << 21)));
            rank[i] = Pb[q] + lp;      // coalesced in i
        }
    }
    __syncthreads();

    int total = min(n - base, PTS_PER_BLK);
    #pragma unroll
    for (int k = 0; k < SC_PPT; ++k) {
        int j = k * SC_THREADS + t;
        if (j < total) {
            float4 pl = payload[j];
            int w = __float_as_int(pl.w);
            int q = w >> 21;
            pl.w = __int_as_float(w & IDXMASK);
            sorted[Pb[q] + (j - cnt[q])] = pl;
        }
    }
}

__device__ __forceinline__ float4 lerp4(float4 a, float4 b, float w) {
    return make_float4(a.x + w * (b.x - a.x),
                       a.y + w * (b.y - a.y),
                       a.z + w * (b.z - a.z),
                       a.w + w * (b.w - a.w));
}

template <int RES>
__device__ __forceinline__ float4 level_val(const float4* __restrict__ V,
                                            float px, float py, float pz) {
    constexpr int S = RES + 1;
    float xs = fmodf(px * (float)RES, (float)RES);
    float ys = fmodf(py * (float)RES, (float)RES);
    float zs = fmodf(pz * (float)RES, (float)RES);
    float fx = floorf(xs), fy = floorf(ys), fz = floorf(zs);
    float tx = xs - fx, ty = ys - fy, tz = zs - fz;
    int ix = (int)fx, iy = (int)fy, iz = (int)fz;

    float wx = (3.0f - 2.0f * tx) * tx * tx;
    float wy = (3.0f - 2.0f * ty) * ty * ty;
    float wz = (3.0f - 2.0f * tz) * tz * tz;

    int base = (ix * S + iy) * S + iz;
    const float4* p0 = V + base;
    const float4* p1 = p0 + S * S;

    float4 c000 = p0[0];
    float4 c001 = p0[1];
    float4 c010 = p0[S];
    float4 c011 = p0[S + 1];
    float4 c100 = p1[0];
    float4 c101 = p1[1];
    float4 c110 = p1[S];
    float4 c111 = p1[S + 1];

    float4 m00 = lerp4(c000, c100, wx);
    float4 m01 = lerp4(c001, c101, wx);
    float4 m10 = lerp4(c010, c110, wx);
    float4 m11 = lerp4(c011, c111, wx);
    float4 n0  = lerp4(m00, m10, wy);
    float4 n1  = lerp4(m01, m11, wy);
    return lerp4(n0, n1, wz);
}

__device__ __forceinline__ float4 composite(const float4* __restrict__ V16,
                                            const float4* __restrict__ V32,
                                            const float4* __restrict__ V64,
                                            const float4* __restrict__ V128,
                                            float px, float py, float pz) {
    float4 acc = level_val<16>(V16, px, py, pz);
    float4 v;
    v = level_val<32>(V32, px, py, pz);
    acc.x += 0.5f * v.x; acc.y += 0.5f * v.y; acc.z += 0.5f * v.z; acc.w += 0.5f * v.w;
    v = level_val<64>(V64, px, py, pz);
    acc.x += 0.25f * v.x; acc.y += 0.25f * v.y; acc.z += 0.25f * v.z; acc.w += 0.25f * v.w;
    v = level_val<128>(V128, px, py, pz);
    acc.x += 0.125f * v.x; acc.y += 0.125f * v.y; acc.z += 0.125f * v.z; acc.w += 0.125f * v.w;
    return acc;
}

// fp16 node load: 8B (4 halves) via one ds_read_b64.
__device__ __forceinline__ float4 ldh4(const uint2* p) {
    uint2 u = *p;
    __half2 h0 = *reinterpret_cast<const __half2*>(&u.x);
    __half2 h1 = *reinterpret_cast<const __half2*>(&u.y);
    float2 f0 = __half22float2(h0);
    float2 f1 = __half22float2(h1);
    return make_float4(f0.x, f0.y, f1.x, f1.y);
}

__device__ __forceinline__ uint2 sth4(float4 v) {
    __half2 h0 = __floats2half2_rn(v.x, v.y);
    __half2 h1 = __floats2half2_rn(v.z, v.w);
    uint2 u;
    u.x = *reinterpret_cast<unsigned int*>(&h0);
    u.y = *reinterpret_cast<unsigned int*>(&h1);
    return u;
}

// Trilinear interp from an fp16 LDS slice covering one FULL coarse bucket
// (1/16 x 1/8 x 1/8). CX=RES/16 cells in x, CY=CZ=RES/8 in y/z. Clamped.
template <int RES>
__device__ __forceinline__ float4 lds_interp_h(const uint2* s,
                                               float px, float py, float pz,
                                               int ix16, int iy8, int iz8) {
    constexpr int CX = RES / 16, CY = RES / 8, CZ = RES / 8;
    constexpr int DY = CY + 1, DZ = CZ + 1;
    float xs = px * (float)RES;
    float ys = py * (float)RES;
    float zs = pz * (float)RES;
    int ixg = (int)xs, iyg = (int)ys, izg = (int)zs;
    float tx = xs - (float)ixg, ty = ys - (float)iyg, tz = zs - (float)izg;
    int lx = min(max(ixg - ix16 * CX, 0), CX - 1);
    int ly = min(max(iyg - iy8 * CY, 0), CY - 1);
    int lz = min(max(izg - iz8 * CZ, 0), CZ - 1);

    float wx = (3.0f - 2.0f * tx) * tx * tx;
    float wy = (3.0f - 2.0f * ty) * ty * ty;
    float wz = (3.0f - 2.0f * tz) * tz * tz;

    const uint2* p0 = s + (lx * DY + ly) * DZ + lz;
    const uint2* p1 = p0 + DY * DZ;
    float4 c000 = ldh4(p0),      c001 = ldh4(p0 + 1);
    float4 c010 = ldh4(p0 + DZ), c011 = ldh4(p0 + DZ + 1);
    float4 c100 = ldh4(p1),      c101 = ldh4(p1 + 1);
    float4 c110 = ldh4(p1 + DZ), c111 = ldh4(p1 + DZ + 1);

    float4 m00 = lerp4(c000, c100, wx);
    float4 m01 = lerp4(c001, c101, wx);
    float4 m10 = lerp4(c010, c110, wx);
    float4 m11 = lerp4(c011, c111, wx);
    float4 n0  = lerp4(m00, m10, wy);
    float4 n1  = lerp4(m01, m11, wy);
    return lerp4(n0, n1, wz);
}

// Same, float4 (fp32) LDS slice — for the high-weight 16/32 levels.
template <int RES>
__device__ __forceinline__ float4 lds_interp_b(const float4* s,
                                               float px, float py, float pz,
                                               int ix16, int iy8, int iz8) {
    constexpr int CX = RES / 16, CY = RES / 8, CZ = RES / 8;
    constexpr int DY = CY + 1, DZ = CZ + 1;
    float xs = px * (float)RES;
    float ys = py * (float)RES;
    float zs = pz * (float)RES;
    int ixg = (int)xs, iyg = (int)ys, izg = (int)zs;
    float tx = xs - (float)ixg, ty = ys - (float)iyg, tz = zs - (float)izg;
    int lx = min(max(ixg - ix16 * CX, 0), CX - 1);
    int ly = min(max(iyg - iy8 * CY, 0), CY - 1);
    int lz = min(max(izg - iz8 * CZ, 0), CZ - 1);

    float wx = (3.0f - 2.0f * tx) * tx * tx;
    float wy = (3.0f - 2.0f * ty) * ty * ty;
    float wz = (3.0f - 2.0f * tz) * tz * tz;

    const float4* p0 = s + (lx * DY + ly) * DZ + lz;
    const float4* p1 = p0 + DY * DZ;
    float4 c000 = p0[0],  c001 = p0[1];
    float4 c010 = p0[DZ], c011 = p0[DZ + 1];
    float4 c100 = p1[0],  c101 = p1[1];
    float4 c110 = p1[DZ], c111 = p1[DZ + 1];

    float4 m00 = lerp4(c000, c100, wx);
    float4 m01 = lerp4(c001, c101, wx);
    float4 m10 = lerp4(c010, c110, wx);
    float4 m11 = lerp4(c011, c111, wx);
    float4 n0  = lerp4(m00, m10, wy);
    float4 n1  = lerp4(m01, m11, wy);
    return lerp4(n0, n1, wz);
}

// One WG per 1/16x1/8x1/8 bucket. ALL levels staged to LDS. Point loop:
// coalesced sorted read, LDS-only eval, COALESCED tmp write. launch_bounds
// min-waves 4 (not 8): VGPR cap 128 so the 4-level eval doesn't spill.
__global__ void __launch_bounds__(MT, 4)
cvn_main4(const float4* __restrict__ sorted, const int* __restrict__ Tbase,
          const float4* __restrict__ V16, const float4* __restrict__ V32,
          const float4* __restrict__ V64, const float4* __restrict__ V128,
          float4* __restrict__ tmp, int n) {
    __shared__ uint2 s128[9 * 17 * 17];   // 2601 -> 20808 B
    __shared__ uint2 s64[5 * 9 * 9];      //  405 ->  3240 B
    __shared__ float4 s32f[3 * 5 * 5];    //   75 ->  1200 B
    __shared__ float4 s16f[2 * 3 * 3];    //   18 ->   288 B
    int t = threadIdx.x, b = blockIdx.x;

    // XCD-compact mapping: b&7 -> octant of the 16x8x8 bucket space.
    int ox = b & 1, oy = (b >> 1) & 1, oz = (b >> 2) & 1;
    int g  = b >> 3;                         // 0..127
    int gx = g >> 4, gy = (g >> 2) & 3, gz = g & 3;
    int ix16 = ox * 8 + gx, iy8 = oy * 4 + gy, iz8 = oz * 4 + gz;
    int q = (ix16 * 8 + iy8) * 8 + iz8;

    int base = Tbase[q];
    int end  = (q == NB - 1) ? n : Tbase[q + 1];
    int len  = end - base;

    // Stage: V128 9x17x17 fp16, V64 5x9x9 fp16, V32 3x5x5 f32, V16 2x3x3 f32.
    int bx = ix16 * 8, by = iy8 * 16, bz = iz8 * 16;
    for (int u = t; u < 2601; u += MT) {
        int a = u / 289, r = u - a * 289;
        int bb = r / 17, c = r - bb * 17;
        s128[u] = sth4(V128[((size_t)(bx + a) * 129 + (by + bb)) * 129
                            + (bz + c)]);
    }
    for (int u = t; u < 405; u += MT) {
        int a = u / 81, r = u - a * 81;
        int bb = r / 9, c = r - bb * 9;
        s64[u] = sth4(V64[((size_t)(ix16 * 4 + a) * 65 + (iy8 * 8 + bb)) * 65
                          + (iz8 * 8 + c)]);
    }
    for (int u = t; u < 75; u += MT) {
        int a = u / 25, r = u - a * 25;
        int bb = r / 5, c = r - bb * 5;
        s32f[u] = V32[((size_t)(ix16 * 2 + a) * 33 + (iy8 * 4 + bb)) * 33
                      + (iz8 * 4 + c)];
    }
    for (int u = t; u < 18; u += MT) {
        int a = u / 9, r = u - a * 9;
        int bb = r / 3, c = r - bb * 3;
        s16f[u] = V16[((size_t)(ix16 + a) * 17 + (iy8 * 2 + bb)) * 17
                      + (iz8 * 2 + c)];
    }
    __syncthreads();

    // Stream points: coalesced read, LDS-only eval, coalesced tmp write.
    for (int p = t; p < len; p += MT) {
        float4 pt = sorted[base + p];
        float4 acc = lds_interp_b<16>(s16f, pt.x, pt.y, pt.z, ix16, iy8, iz8);
        float4 v;
        v = lds_interp_b<32>(s32f, pt.x, pt.y, pt.z, ix16, iy8, iz8);
        acc.x += 0.5f * v.x; acc.y += 0.5f * v.y;
        acc.z += 0.5f * v.z; acc.w += 0.5f * v.w;
        v = lds_interp_h<64>(s64, pt.x, pt.y, pt.z, ix16, iy8, iz8);
        acc.x += 0.25f * v.x; acc.y += 0.25f * v.y;
        acc.z += 0.25f * v.z; acc.w += 0.25f * v.w;
        v = lds_interp_h<128>(s128, pt.x, pt.y, pt.z, ix16, iy8, iz8);
        acc.x += 0.125f * v.x; acc.y += 0.125f * v.y;
        acc.z += 0.125f * v.z; acc.w += 0.125f * v.w;
        tmp[base + p] = acc;
    }
}

// Gather epilogue: out[i] = tmp[rank[i]] (rank coalesced; tmp via L3).
__global__ void __launch_bounds__(256)
cvn_permute(const float4* __restrict__ tmp, const int* __restrict__ rank,
            float4* __restrict__ out, int n) {
    int i = blockIdx.x * 256 + (int)threadIdx.x;
    if (i >= n) return;
    out[i] = tmp[rank[i]];
}

__global__ void __launch_bounds__(256)
cvn_direct(const float* __restrict__ x,
           const float4* __restrict__ V16, const float4* __restrict__ V32,
           const float4* __restrict__ V64, const float4* __restrict__ V128,
           float4* __restrict__ out, int n) {
    int i = blockIdx.x * blockDim.x + threadIdx.x;
    if (i >= n) return;
    out[i] = composite(V16, V32, V64, V128, x[3 * i], x[3 * i + 1], x[3 * i + 2]);
}

extern "C" void kernel_launch(void* const* d_in, const int* in_sizes, int n_in,
                              void* d_out, int out_size, void* d_ws, size_t ws_size,
                              hipStream_t stream) {
    const float*  x    = (const float*)d_in[0];
    const float4* V16  = (const float4*)d_in[1];
    const float4* V32  = (const float4*)d_in[2];
    const float4* V64  = (const float4*)d_in[3];
    const float4* V128 = (const float4*)d_in[4];
    float4* out = (float4*)d_out;

    int n = in_sizes[0] / 3;
    int nblk = (n + PTS_PER_BLK - 1) / PTS_PER_BLK;
    int nch  = (nblk + CHUNK - 1) / CHUNK;

    auto align256 = [](size_t v) { return (v + 255) & ~(size_t)255; };
    size_t offP      = 0;
    size_t offS      = align256(offP + (size_t)nblk * NB * sizeof(int));
    size_t offSorted = align256(offS + (size_t)nch * NB * sizeof(int));
    size_t offRank   = align256(offSorted + (size_t)n * sizeof(float4));
    size_t offTmp    = align256(offRank + (size_t)n * sizeof(int));
    size_t need      = offTmp + (size_t)n * sizeof(float4);

    int grid256 = (n + 255) / 256;

    if (ws_size >= need) {
        int*    P      = (int*)((char*)d_ws + offP);
        int*    S      = (int*)((char*)d_ws + offS);
        float4* sorted = (float4*)((char*)d_ws + offSorted);
        int*    rank   = (int*)((char*)d_ws + offRank);
        float4* tmp    = (float4*)((char*)d_ws + offTmp);

        hipMemsetAsync(S, 0, (size_t)nch * NB * sizeof(int), stream);
        cvn_hist<<<nblk, H_THREADS, 0, stream>>>(x, P, S, n);
        cvn_scan_b<<<1, NB, 0, stream>>>(S, nch);
        cvn_scan_c<<<dim3(NB / 256, nch), 256, 0, stream>>>(P, S, nblk);
        cvn_scatter<<<nblk, SC_THREADS, 0, stream>>>(x, P, sorted, rank, n);
        cvn_main4<<<NB, MT, 0, stream>>>(sorted, S, V16, V32, V64, V128,
                                         tmp, n);
        cvn_permute<<<grid256, 256, 0, stream>>>(tmp, rank, out, n);
    } else {
        cvn_direct<<<grid256, 256, 0, stream>>>(x, V16, V32, V64, V128, out, n);
    }
}

// Round 12
// 181.916 us; speedup vs baseline: 2.3092x; 1.1351x over previous
//
#include <hip/hip_runtime.h>
#include <hip/hip_fp16.h>

// CompositeValueNoise R18: R17 base (verified 206.5us; main4 46us/38F/32W,
// VGPR=64 with (512,4) bound -- spill mechanism CONFIRMED and closed).
// One structural change: main4 writes out[orig] directly (idx rides in
// sorted .w), deleting rank writes + tmp + permute (~33us + 16MB traffic).
// Safe now: the scattered write was only ever pathological when main4
// spilled (R11-R16); with VGPR cap 128 and measured use 64 there is
// headroom. Expected main4 ~53us / ~64MB W (R10b/R13 signature).
// Hazard watch: main4 WRITE >= 150MB falsifies the closed spill story.

#define NB 1024                // 16 x 8 x 8 buckets
#define PTS_PER_BLK 4096
#define CHUNK 32
#define SC_THREADS 1024
#define SC_PPT (PTS_PER_BLK / SC_THREADS)
#define H_THREADS 256
#define H_PPT (PTS_PER_BLK / H_THREADS)
#define MT 512                 // main kernel threads
#define IDXMASK 0x1FFFFF       // n < 2^21

__device__ __forceinline__ int bucket_of(float px, float py, float pz) {
    int ix = min(max((int)(px * 16.0f), 0), 15);
    int iy = min(max((int)(py * 8.0f), 0), 7);
    int iz = min(max((int)(pz * 8.0f), 0), 7);
    return (ix * 8 + iy) * 8 + iz;
}

// Per-block counts -> P[b][q]; chunk sums accumulated into S[c][q]
// (S pre-zeroed; integer atomic adds -> bit-identical to old scan_a).
__global__ void __launch_bounds__(H_THREADS)
cvn_hist(const float* __restrict__ x, int* __restrict__ P,
         int* __restrict__ S, int n) {
    __shared__ int cnt[NB];
    int t = threadIdx.x;
    for (int q = t; q < NB; q += H_THREADS) cnt[q] = 0;
    __syncthreads();
    int base = blockIdx.x * PTS_PER_BLK;
    for (int k = 0; k < H_PPT; ++k) {
        int i = base + k * H_THREADS + t;
        if (i < n)
            atomicAdd(&cnt[bucket_of(x[3 * i], x[3 * i + 1], x[3 * i + 2])], 1);
    }
    __syncthreads();
    int* Pb = P + (size_t)blockIdx.x * NB;
    int* Sc = S + (size_t)(blockIdx.x / CHUNK) * NB;
    for (int q = t; q < NB; q += H_THREADS) {
        int v = cnt[q];
        Pb[q] = v;
        if (v) atomicAdd(&Sc[q], v);
    }
}

// After: S[c][q] = Texcl[q] + exclusive chunk prefix; S[0][q] = bucket base.
__global__ void __launch_bounds__(NB)
cvn_scan_b(int* __restrict__ S, int nch) {
    __shared__ int part[16];
    int t = threadIdx.x;
    int lane = t & 63, wid = t >> 6;
    int acc = 0;
    for (int c = 0; c < nch; ++c) {
        int v = S[(size_t)c * NB + t];
        S[(size_t)c * NB + t] = acc;
        acc += v;
    }
    int sum = acc;
    #pragma unroll
    for (int off = 1; off < 64; off <<= 1) {
        int v = __shfl_up(sum, off, 64);
        if (lane >= off) sum += v;
    }
    if (lane == 63) part[wid] = sum;
    __syncthreads();
    if (t < 16) {
        int p = part[t];
        int s2 = p;
        #pragma unroll
        for (int off = 1; off < 16; off <<= 1) {
            int v = __shfl_up(s2, off, 64);
            if (t >= off) s2 += v;
        }
        part[t] = s2 - p;          // exclusive wave offset
    }
    __syncthreads();
    int texcl = part[wid] + (sum - acc);   // global exclusive prefix at t
    for (int c = 0; c < nch; ++c) S[(size_t)c * NB + t] += texcl;
}

__global__ void __launch_bounds__(256)
cvn_scan_c(int* __restrict__ P, const int* __restrict__ S, int nblk) {
    int q = blockIdx.x * 256 + threadIdx.x;
    int c = blockIdx.y;
    int b0 = c * CHUNK, b1 = min(b0 + CHUNK, nblk);
    int run = S[(size_t)c * NB + q];
    for (int b = b0; b < b1; ++b) {
        int v = P[(size_t)b * NB + q];
        P[(size_t)b * NB + q] = run;
        run += v;
    }
}

// Deterministic (stable) scatter; q packed into payload.w; 2-barrier scan.
__global__ void __launch_bounds__(SC_THREADS, 8)
cvn_scatter(const float* __restrict__ x, const int* __restrict__ P,
            float4* __restrict__ sorted, int n) {
    __shared__ int cnt[NB];       //  counts -> exclusive staging starts
    __shared__ int place[NB];
    __shared__ int Pb[NB];
    __shared__ int part[16];
    __shared__ float4 payload[PTS_PER_BLK];   // 64KB
    int t = threadIdx.x, b = blockIdx.x;
    int lane = t & 63, wid = t >> 6;
    int base = b * PTS_PER_BLK;
    cnt[t] = 0; place[t] = 0;
    Pb[t] = P[(size_t)b * NB + t];
    __syncthreads();

    float px[SC_PPT], py[SC_PPT], pz[SC_PPT];
    int qq[SC_PPT];
    #pragma unroll
    for (int k = 0; k < SC_PPT; ++k) {
        int i = base + k * SC_THREADS + t;
        if (i < n) {
            px[k] = x[3 * i]; py[k] = x[3 * i + 1]; pz[k] = x[3 * i + 2];
            qq[k] = bucket_of(px[k], py[k], pz[k]);
            atomicAdd(&cnt[qq[k]], 1);
        } else qq[k] = -1;
    }
    __syncthreads();

    // Exclusive scan of cnt[1024]: per-wave shfl scan + 16-partial scan.
    int c0 = cnt[t];
    int sum = c0;
    #pragma unroll
    for (int off = 1; off < 64; off <<= 1) {
        int v = __shfl_up(sum, off, 64);
        if (lane >= off) sum += v;
    }
    if (lane == 63) part[wid] = sum;
    __syncthreads();
    if (t < 16) {
        int p = part[t];
        int s2 = p;
        #pragma unroll
        for (int off = 1; off < 16; off <<= 1) {
            int v = __shfl_up(s2, off, 64);
            if (t >= off) s2 += v;
        }
        part[t] = s2 - p;          // exclusive wave offset
    }
    __syncthreads();
    cnt[t] = part[wid] + (sum - c0);   // exclusive staging start
    __syncthreads();

    #pragma unroll
    for (int k = 0; k < SC_PPT; ++k) {
        if (qq[k] >= 0) {
            int q = qq[k];
            int lp = atomicAdd(&place[q], 1);
            int slot = cnt[q] + lp;
            int i = base + k * SC_THREADS + t;
            payload[slot] = make_float4(px[k], py[k], pz[k],
                                        __int_as_float(i | (q << 21)));
        }
    }
    __syncthreads();

    int total = min(n - base, PTS_PER_BLK);
    #pragma unroll
    for (int k = 0; k < SC_PPT; ++k) {
        int j = k * SC_THREADS + t;
        if (j < total) {
            float4 pl = payload[j];
            int w = __float_as_int(pl.w);
            int q = w >> 21;
            pl.w = __int_as_float(w & IDXMASK);
            sorted[Pb[q] + (j - cnt[q])] = pl;
        }
    }
}

__device__ __forceinline__ float4 lerp4(float4 a, float4 b, float w) {
    return make_float4(a.x + w * (b.x - a.x),
                       a.y + w * (b.y - a.y),
                       a.z + w * (b.z - a.z),
                       a.w + w * (b.w - a.w));
}

template <int RES>
__device__ __forceinline__ float4 level_val(const float4* __restrict__ V,
                                            float px, float py, float pz) {
    constexpr int S = RES + 1;
    float xs = fmodf(px * (float)RES, (float)RES);
    float ys = fmodf(py * (float)RES, (float)RES);
    float zs = fmodf(pz * (float)RES, (float)RES);
    float fx = floorf(xs), fy = floorf(ys), fz = floorf(zs);
    float tx = xs - fx, ty = ys - fy, tz = zs - fz;
    int ix = (int)fx, iy = (int)fy, iz = (int)fz;

    float wx = (3.0f - 2.0f * tx) * tx * tx;
    float wy = (3.0f - 2.0f * ty) * ty * ty;
    float wz = (3.0f - 2.0f * tz) * tz * tz;

    int base = (ix * S + iy) * S + iz;
    const float4* p0 = V + base;
    const float4* p1 = p0 + S * S;

    float4 c000 = p0[0];
    float4 c001 = p0[1];
    float4 c010 = p0[S];
    float4 c011 = p0[S + 1];
    float4 c100 = p1[0];
    float4 c101 = p1[1];
    float4 c110 = p1[S];
    float4 c111 = p1[S + 1];

    float4 m00 = lerp4(c000, c100, wx);
    float4 m01 = lerp4(c001, c101, wx);
    float4 m10 = lerp4(c010, c110, wx);
    float4 m11 = lerp4(c011, c111, wx);
    float4 n0  = lerp4(m00, m10, wy);
    float4 n1  = lerp4(m01, m11, wy);
    return lerp4(n0, n1, wz);
}

__device__ __forceinline__ float4 composite(const float4* __restrict__ V16,
                                            const float4* __restrict__ V32,
                                            const float4* __restrict__ V64,
                                            const float4* __restrict__ V128,
                                            float px, float py, float pz) {
    float4 acc = level_val<16>(V16, px, py, pz);
    float4 v;
    v = level_val<32>(V32, px, py, pz);
    acc.x += 0.5f * v.x; acc.y += 0.5f * v.y; acc.z += 0.5f * v.z; acc.w += 0.5f * v.w;
    v = level_val<64>(V64, px, py, pz);
    acc.x += 0.25f * v.x; acc.y += 0.25f * v.y; acc.z += 0.25f * v.z; acc.w += 0.25f * v.w;
    v = level_val<128>(V128, px, py, pz);
    acc.x += 0.125f * v.x; acc.y += 0.125f * v.y; acc.z += 0.125f * v.z; acc.w += 0.125f * v.w;
    return acc;
}

// fp16 node load: 8B (4 halves) via one ds_read_b64.
__device__ __forceinline__ float4 ldh4(const uint2* p) {
    uint2 u = *p;
    __half2 h0 = *reinterpret_cast<const __half2*>(&u.x);
    __half2 h1 = *reinterpret_cast<const __half2*>(&u.y);
    float2 f0 = __half22float2(h0);
    float2 f1 = __half22float2(h1);
    return make_float4(f0.x, f0.y, f1.x, f1.y);
}

__device__ __forceinline__ uint2 sth4(float4 v) {
    __half2 h0 = __floats2half2_rn(v.x, v.y);
    __half2 h1 = __floats2half2_rn(v.z, v.w);
    uint2 u;
    u.x = *reinterpret_cast<unsigned int*>(&h0);
    u.y = *reinterpret_cast<unsigned int*>(&h1);
    return u;
}

// Trilinear interp from an fp16 LDS slice covering one FULL coarse bucket
// (1/16 x 1/8 x 1/8). CX=RES/16 cells in x, CY=CZ=RES/8 in y/z. Clamped.
template <int RES>
__device__ __forceinline__ float4 lds_interp_h(const uint2* s,
                                               float px, float py, float pz,
                                               int ix16, int iy8, int iz8) {
    constexpr int CX = RES / 16, CY = RES / 8, CZ = RES / 8;
    constexpr int DY = CY + 1, DZ = CZ + 1;
    float xs = px * (float)RES;
    float ys = py * (float)RES;
    float zs = pz * (float)RES;
    int ixg = (int)xs, iyg = (int)ys, izg = (int)zs;
    float tx = xs - (float)ixg, ty = ys - (float)iyg, tz = zs - (float)izg;
    int lx = min(max(ixg - ix16 * CX, 0), CX - 1);
    int ly = min(max(iyg - iy8 * CY, 0), CY - 1);
    int lz = min(max(izg - iz8 * CZ, 0), CZ - 1);

    float wx = (3.0f - 2.0f * tx) * tx * tx;
    float wy = (3.0f - 2.0f * ty) * ty * ty;
    float wz = (3.0f - 2.0f * tz) * tz * tz;

    const uint2* p0 = s + (lx * DY + ly) * DZ + lz;
    const uint2* p1 = p0 + DY * DZ;
    float4 c000 = ldh4(p0),      c001 = ldh4(p0 + 1);
    float4 c010 = ldh4(p0 + DZ), c011 = ldh4(p0 + DZ + 1);
    float4 c100 = ldh4(p1),      c101 = ldh4(p1 + 1);
    float4 c110 = ldh4(p1 + DZ), c111 = ldh4(p1 + DZ + 1);

    float4 m00 = lerp4(c000, c100, wx);
    float4 m01 = lerp4(c001, c101, wx);
    float4 m10 = lerp4(c010, c110, wx);
    float4 m11 = lerp4(c011, c111, wx);
    float4 n0  = lerp4(m00, m10, wy);
    float4 n1  = lerp4(m01, m11, wy);
    return lerp4(n0, n1, wz);
}

// Same, float4 (fp32) LDS slice — for the high-weight 16/32 levels.
template <int RES>
__device__ __forceinline__ float4 lds_interp_b(const float4* s,
                                               float px, float py, float pz,
                                               int ix16, int iy8, int iz8) {
    constexpr int CX = RES / 16, CY = RES / 8, CZ = RES / 8;
    constexpr int DY = CY + 1, DZ = CZ + 1;
    float xs = px * (float)RES;
    float ys = py * (float)RES;
    float zs = pz * (float)RES;
    int ixg = (int)xs, iyg = (int)ys, izg = (int)zs;
    float tx = xs - (float)ixg, ty = ys - (float)iyg, tz = zs - (float)izg;
    int lx = min(max(ixg - ix16 * CX, 0), CX - 1);
    int ly = min(max(iyg - iy8 * CY, 0), CY - 1);
    int lz = min(max(izg - iz8 * CZ, 0), CZ - 1);

    float wx = (3.0f - 2.0f * tx) * tx * tx;
    float wy = (3.0f - 2.0f * ty) * ty * ty;
    float wz = (3.0f - 2.0f * tz) * tz * tz;

    const float4* p0 = s + (lx * DY + ly) * DZ + lz;
    const float4* p1 = p0 + DY * DZ;
    float4 c000 = p0[0],  c001 = p0[1];
    float4 c010 = p0[DZ], c011 = p0[DZ + 1];
    float4 c100 = p1[0],  c101 = p1[1];
    float4 c110 = p1[DZ], c111 = p1[DZ + 1];

    float4 m00 = lerp4(c000, c100, wx);
    float4 m01 = lerp4(c001, c101, wx);
    float4 m10 = lerp4(c010, c110, wx);
    float4 m11 = lerp4(c011, c111, wx);
    float4 n0  = lerp4(m00, m10, wy);
    float4 n1  = lerp4(m01, m11, wy);
    return lerp4(n0, n1, wz);
}

// One WG per 1/16x1/8x1/8 bucket. ALL levels staged to LDS. Point loop:
// coalesced sorted read, LDS-only eval, direct scattered out[orig] write.
// launch_bounds min-waves 4: VGPR cap 128 so the 4-level eval never spills.
__global__ void __launch_bounds__(MT, 4)
cvn_main4(const float4* __restrict__ sorted, const int* __restrict__ Tbase,
          const float4* __restrict__ V16, const float4* __restrict__ V32,
          const float4* __restrict__ V64, const float4* __restrict__ V128,
          float4* __restrict__ out, int n) {
    __shared__ uint2 s128[9 * 17 * 17];   // 2601 -> 20808 B
    __shared__ uint2 s64[5 * 9 * 9];      //  405 ->  3240 B
    __shared__ float4 s32f[3 * 5 * 5];    //   75 ->  1200 B
    __shared__ float4 s16f[2 * 3 * 3];    //   18 ->   288 B
    int t = threadIdx.x, b = blockIdx.x;

    // XCD-compact mapping: b&7 -> octant of the 16x8x8 bucket space.
    int ox = b & 1, oy = (b >> 1) & 1, oz = (b >> 2) & 1;
    int g  = b >> 3;                         // 0..127
    int gx = g >> 4, gy = (g >> 2) & 3, gz = g & 3;
    int ix16 = ox * 8 + gx, iy8 = oy * 4 + gy, iz8 = oz * 4 + gz;
    int q = (ix16 * 8 + iy8) * 8 + iz8;

    int base = Tbase[q];
    int end  = (q == NB - 1) ? n : Tbase[q + 1];
    int len  = end - base;

    // Stage: V128 9x17x17 fp16, V64 5x9x9 fp16, V32 3x5x5 f32, V16 2x3x3 f32.
    int bx = ix16 * 8, by = iy8 * 16, bz = iz8 * 16;
    for (int u = t; u < 2601; u += MT) {
        int a = u / 289, r = u - a * 289;
        int bb = r / 17, c = r - bb * 17;
        s128[u] = sth4(V128[((size_t)(bx + a) * 129 + (by + bb)) * 129
                            + (bz + c)]);
    }
    for (int u = t; u < 405; u += MT) {
        int a = u / 81, r = u - a * 81;
        int bb = r / 9, c = r - bb * 9;
        s64[u] = sth4(V64[((size_t)(ix16 * 4 + a) * 65 + (iy8 * 8 + bb)) * 65
                          + (iz8 * 8 + c)]);
    }
    for (int u = t; u < 75; u += MT) {
        int a = u / 25, r = u - a * 25;
        int bb = r / 5, c = r - bb * 5;
        s32f[u] = V32[((size_t)(ix16 * 2 + a) * 33 + (iy8 * 4 + bb)) * 33
                      + (iz8 * 4 + c)];
    }
    for (int u = t; u < 18; u += MT) {
        int a = u / 9, r = u - a * 9;
        int bb = r / 3, c = r - bb * 3;
        s16f[u] = V16[((size_t)(ix16 + a) * 17 + (iy8 * 2 + bb)) * 17
                      + (iz8 * 2 + c)];
    }
    __syncthreads();

    // Stream points: coalesced read, LDS-only eval, scattered out write.
    for (int p = t; p < len; p += MT) {
        float4 pt = sorted[base + p];
        float4 acc = lds_interp_b<16>(s16f, pt.x, pt.y, pt.z, ix16, iy8, iz8);
        float4 v;
        v = lds_interp_b<32>(s32f, pt.x, pt.y, pt.z, ix16, iy8, iz8);
        acc.x += 0.5f * v.x; acc.y += 0.5f * v.y;
        acc.z += 0.5f * v.z; acc.w += 0.5f * v.w;
        v = lds_interp_h<64>(s64, pt.x, pt.y, pt.z, ix16, iy8, iz8);
        acc.x += 0.25f * v.x; acc.y += 0.25f * v.y;
        acc.z += 0.25f * v.z; acc.w += 0.25f * v.w;
        v = lds_interp_h<128>(s128, pt.x, pt.y, pt.z, ix16, iy8, iz8);
        acc.x += 0.125f * v.x; acc.y += 0.125f * v.y;
        acc.z += 0.125f * v.z; acc.w += 0.125f * v.w;
        out[__float_as_int(pt.w)] = acc;
    }
}

__global__ void __launch_bounds__(256)
cvn_direct(const float* __restrict__ x,
           const float4* __restrict__ V16, const float4* __restrict__ V32,
           const float4* __restrict__ V64, const float4* __restrict__ V128,
           float4* __restrict__ out, int n) {
    int i = blockIdx.x * blockDim.x + threadIdx.x;
    if (i >= n) return;
    out[i] = composite(V16, V32, V64, V128, x[3 * i], x[3 * i + 1], x[3 * i + 2]);
}

extern "C" void kernel_launch(void* const* d_in, const int* in_sizes, int n_in,
                              void* d_out, int out_size, void* d_ws, size_t ws_size,
                              hipStream_t stream) {
    const float*  x    = (const float*)d_in[0];
    const float4* V16  = (const float4*)d_in[1];
    const float4* V32  = (const float4*)d_in[2];
    const float4* V64  = (const float4*)d_in[3];
    const float4* V128 = (const float4*)d_in[4];
    float4* out = (float4*)d_out;

    int n = in_sizes[0] / 3;
    int nblk = (n + PTS_PER_BLK - 1) / PTS_PER_BLK;
    int nch  = (nblk + CHUNK - 1) / CHUNK;

    auto align256 = [](size_t v) { return (v + 255) & ~(size_t)255; };
    size_t offP      = 0;
    size_t offS      = align256(offP + (size_t)nblk * NB * sizeof(int));
    size_t offSorted = align256(offS + (size_t)nch * NB * sizeof(int));
    size_t need      = offSorted + (size_t)n * sizeof(float4);

    int grid256 = (n + 255) / 256;

    if (ws_size >= need) {
        int*    P      = (int*)((char*)d_ws + offP);
        int*    S      = (int*)((char*)d_ws + offS);
        float4* sorted = (float4*)((char*)d_ws + offSorted);

        hipMemsetAsync(S, 0, (size_t)nch * NB * sizeof(int), stream);
        cvn_hist<<<nblk, H_THREADS, 0, stream>>>(x, P, S, n);
        cvn_scan_b<<<1, NB, 0, stream>>>(S, nch);
        cvn_scan_c<<<dim3(NB / 256, nch), 256, 0, stream>>>(P, S, nblk);
        cvn_scatter<<<nblk, SC_THREADS, 0, stream>>>(x, P, sorted, n);
        cvn_main4<<<NB, MT, 0, stream>>>(sorted, S, V16, V32, V64, V128,
                                         out, n);
    } else {
        cvn_direct<<<grid256, 256, 0, stream>>>(x, V16, V32, V64, V128, out, n);
    }
}